// Round 2
// baseline (4146.876 us; speedup 1.0000x reference)
//
#include <hip/hip_runtime.h>
#include <math.h>

namespace {

constexpr int Bsz  = 16384;
constexpr int Fdim = 512;
constexpr int Hdim = 512;
constexpr int Edim = 128;
constexpr int Vdim = 128;
constexpr int Lmsg = 10;
constexpr int H3   = 3 * Hdim;   // 1536

// padded LDS row pitch for the transposed A tiles: 132 -> store-bank =
// (4*(acol+i)+arow)%32, 2-way max (free) instead of 4-way at pitch 128.
constexpr int APAD = 132;

__device__ __forceinline__ float sigm(float x) { return 1.0f / (1.0f + __expf(-x)); }

// ---------------------------------------------------------------------------
// emb_k[v][j] = sum_e embedding[v][e] * gru_kernel[e][j] + bias0[j]
// (folds the input-side GRU matmul into a 128-row lookup table)
// Also zero-inits sym[] for safety.
// ---------------------------------------------------------------------------
__global__ void k_embk(const float* __restrict__ emb, const float* __restrict__ gk,
                       const float* __restrict__ bias0, float* __restrict__ emb_k,
                       int* __restrict__ sym) {
    const int gid = blockIdx.x * 256 + threadIdx.x;       // V*H3 = 196608 threads
    const int v = gid / H3, j = gid - v * H3;
    float acc = bias0[j];
    const float* er = emb + v * Edim;
    #pragma unroll 4
    for (int e = 0; e < Edim; ++e) acc = fmaf(er[e], gk[e * H3 + j], acc);
    emb_k[gid] = acc;
    if (gid < Bsz) sym[gid] = 0;
}

// ---------------------------------------------------------------------------
// h0 = tanh(inputs @ W_vh + b_vh)    [B,512]x[512,512]
// BM=128, BN=64, BK=16, 256 threads, each 8x4 outputs.
// ---------------------------------------------------------------------------
__global__ __launch_bounds__(256, 2) void k_vision(const float* __restrict__ A,
                                                   const float* __restrict__ W,
                                                   const float* __restrict__ bias,
                                                   float* __restrict__ C) {
    __shared__ float As[16][APAD];  // transposed A tile (padded)
    __shared__ float Bs[16][64];
    const int tid = threadIdx.x;
    const int tx = tid & 15, ty = tid >> 4;
    const int r0 = blockIdx.y * 128, c0 = blockIdx.x * 64;

    const int arow = tid >> 2;          // 0..63
    const int acol = (tid & 3) * 4;     // k offset in chunk
    const int bk   = tid >> 4;          // 0..15
    const int bcol = (tid & 15) * 4;

    const float* Abase = A + r0 * Fdim;
    float acc[8][4] = {};

    float4 pa0 = *(const float4*)(Abase + arow * Fdim + acol);
    float4 pa1 = *(const float4*)(Abase + (arow + 64) * Fdim + acol);
    float4 pb  = *(const float4*)(W + bk * Hdim + c0 + bcol);

    for (int kc = 0; kc < Fdim / 16; ++kc) {
        __syncthreads();
        As[acol + 0][arow] = pa0.x;  As[acol + 1][arow] = pa0.y;
        As[acol + 2][arow] = pa0.z;  As[acol + 3][arow] = pa0.w;
        As[acol + 0][arow + 64] = pa1.x;  As[acol + 1][arow + 64] = pa1.y;
        As[acol + 2][arow + 64] = pa1.z;  As[acol + 3][arow + 64] = pa1.w;
        *(float4*)&Bs[bk][bcol] = pb;
        __syncthreads();
        if (kc + 1 < Fdim / 16) {
            const int k0 = (kc + 1) * 16;
            pa0 = *(const float4*)(Abase + arow * Fdim + k0 + acol);
            pa1 = *(const float4*)(Abase + (arow + 64) * Fdim + k0 + acol);
            pb  = *(const float4*)(W + (k0 + bk) * Hdim + c0 + bcol);
        }
        #pragma unroll
        for (int k = 0; k < 16; ++k) {
            const float4 a0 = *(const float4*)&As[k][ty * 8];
            const float4 a1 = *(const float4*)&As[k][ty * 8 + 4];
            const float4 b  = *(const float4*)&Bs[k][tx * 4];
            const float av[8] = {a0.x,a0.y,a0.z,a0.w,a1.x,a1.y,a1.z,a1.w};
            const float bv[4] = {b.x,b.y,b.z,b.w};
            #pragma unroll
            for (int i = 0; i < 8; ++i)
                #pragma unroll
                for (int n = 0; n < 4; ++n)
                    acc[i][n] = fmaf(av[i], bv[n], acc[i][n]);
        }
    }
    const float4 bb = *(const float4*)(bias + c0 + tx * 4);
    #pragma unroll
    for (int i = 0; i < 8; ++i) {
        const int r = r0 + ty * 8 + i;
        float4 o;
        o.x = tanhf(acc[i][0] + bb.x);
        o.y = tanhf(acc[i][1] + bb.y);
        o.z = tanhf(acc[i][2] + bb.z);
        o.w = tanhf(acc[i][3] + bb.w);
        *(float4*)(C + r * Hdim + c0 + tx * 4) = o;
    }
}

// ---------------------------------------------------------------------------
// Fused recurrent step: hz = h @ Uk (+bias1), combined with xz from emb_k[sym]
// (or bias0 at step 0) -> full GRU cell -> hnext.
// Block computes the SAME j-slice of all three gates (z|r|h), so the cell
// update is done entirely in the epilogue. h double-buffered (hcur != hnext).
// BM=128, BN=64, BK=16, 256 threads, 3x8x4 accumulators.
// ---------------------------------------------------------------------------
__global__ __launch_bounds__(256, 2) void k_gru(const float* __restrict__ hcur,
                                                const float* __restrict__ Uk,     // [H,3H]
                                                const float* __restrict__ gbias,  // [2][3H]
                                                const float* __restrict__ emb_k,  // [V][3H]
                                                const int* __restrict__ sym,
                                                int step,
                                                float* __restrict__ hnext) {
    __shared__ float As[16][APAD];
    __shared__ float Bs[3][16][64];
    const int tid = threadIdx.x;
    const int tx = tid & 15, ty = tid >> 4;
    const int r0 = blockIdx.y * 128, c0 = blockIdx.x * 64;

    const int arow = tid >> 2;
    const int acol = (tid & 3) * 4;
    const int bk   = tid >> 4;
    const int bcol = (tid & 15) * 4;

    const float* Abase = hcur + r0 * Hdim;
    float acc[3][8][4] = {};

    float4 pa0 = *(const float4*)(Abase + arow * Hdim + acol);
    float4 pa1 = *(const float4*)(Abase + (arow + 64) * Hdim + acol);
    float4 pb[3];
    #pragma unroll
    for (int g = 0; g < 3; ++g)
        pb[g] = *(const float4*)(Uk + bk * H3 + g * Hdim + c0 + bcol);

    for (int kc = 0; kc < Hdim / 16; ++kc) {
        __syncthreads();
        As[acol + 0][arow] = pa0.x;  As[acol + 1][arow] = pa0.y;
        As[acol + 2][arow] = pa0.z;  As[acol + 3][arow] = pa0.w;
        As[acol + 0][arow + 64] = pa1.x;  As[acol + 1][arow + 64] = pa1.y;
        As[acol + 2][arow + 64] = pa1.z;  As[acol + 3][arow + 64] = pa1.w;
        #pragma unroll
        for (int g = 0; g < 3; ++g) *(float4*)&Bs[g][bk][bcol] = pb[g];
        __syncthreads();
        if (kc + 1 < Hdim / 16) {
            const int k0 = (kc + 1) * 16;
            pa0 = *(const float4*)(Abase + arow * Hdim + k0 + acol);
            pa1 = *(const float4*)(Abase + (arow + 64) * Hdim + k0 + acol);
            #pragma unroll
            for (int g = 0; g < 3; ++g)
                pb[g] = *(const float4*)(Uk + (k0 + bk) * H3 + g * Hdim + c0 + bcol);
        }
        #pragma unroll
        for (int k = 0; k < 16; ++k) {
            const float4 a0 = *(const float4*)&As[k][ty * 8];
            const float4 a1 = *(const float4*)&As[k][ty * 8 + 4];
            const float4 bz = *(const float4*)&Bs[0][k][tx * 4];
            const float4 br = *(const float4*)&Bs[1][k][tx * 4];
            const float4 bh = *(const float4*)&Bs[2][k][tx * 4];
            const float av[8]  = {a0.x,a0.y,a0.z,a0.w,a1.x,a1.y,a1.z,a1.w};
            const float bzv[4] = {bz.x,bz.y,bz.z,bz.w};
            const float brv[4] = {br.x,br.y,br.z,br.w};
            const float bhv[4] = {bh.x,bh.y,bh.z,bh.w};
            #pragma unroll
            for (int i = 0; i < 8; ++i) {
                #pragma unroll
                for (int n = 0; n < 4; ++n) {
                    acc[0][i][n] = fmaf(av[i], bzv[n], acc[0][i][n]);
                    acc[1][i][n] = fmaf(av[i], brv[n], acc[1][i][n]);
                    acc[2][i][n] = fmaf(av[i], bhv[n], acc[2][i][n]);
                }
            }
        }
    }

    // ---- GRU cell epilogue ----
    const int jc = c0 + tx * 4;
    const float* bias1 = gbias + H3;
    const float4 b1z = *(const float4*)(bias1 + jc);
    const float4 b1r = *(const float4*)(bias1 + Hdim + jc);
    const float4 b1h = *(const float4*)(bias1 + 2 * Hdim + jc);
    #pragma unroll
    for (int i = 0; i < 8; ++i) {
        const int r = r0 + ty * 8 + i;
        const float* xrow = (step == 0) ? gbias : (emb_k + sym[r] * H3);  // emb_k includes bias0
        const float4 xz = *(const float4*)(xrow + jc);
        const float4 xr = *(const float4*)(xrow + Hdim + jc);
        const float4 xh = *(const float4*)(xrow + 2 * Hdim + jc);
        const float4 ho = *(const float4*)(hcur + r * Hdim + jc);
        float4 o;
        {
            const float z  = sigm(xz.x + b1z.x + acc[0][i][0]);
            const float rr = sigm(xr.x + b1r.x + acc[1][i][0]);
            const float hh = tanhf(xh.x + rr * (b1h.x + acc[2][i][0]));
            o.x = z * ho.x + (1.0f - z) * hh;
        }
        {
            const float z  = sigm(xz.y + b1z.y + acc[0][i][1]);
            const float rr = sigm(xr.y + b1r.y + acc[1][i][1]);
            const float hh = tanhf(xh.y + rr * (b1h.y + acc[2][i][1]));
            o.y = z * ho.y + (1.0f - z) * hh;
        }
        {
            const float z  = sigm(xz.z + b1z.z + acc[0][i][2]);
            const float rr = sigm(xr.z + b1r.z + acc[1][i][2]);
            const float hh = tanhf(xh.z + rr * (b1h.z + acc[2][i][2]));
            o.z = z * ho.z + (1.0f - z) * hh;
        }
        {
            const float z  = sigm(xz.w + b1z.w + acc[0][i][3]);
            const float rr = sigm(xr.w + b1r.w + acc[1][i][3]);
            const float hh = tanhf(xh.w + rr * (b1h.w + acc[2][i][3]));
            o.w = z * ho.w + (1.0f - z) * hh;
        }
        *(float4*)(hnext + r * Hdim + jc) = o;
    }
}

// ---------------------------------------------------------------------------
// Output head: logits = h_t @ W_out + b_out (BN = V = 128 full width), then
// per-row log-softmax / entropy / argmax fused in the epilogue.
// BM=64, BK=16, 256 threads, each 4x8 outputs (cols tx*4 and 64+tx*4).
// ---------------------------------------------------------------------------
__global__ __launch_bounds__(256, 2) void k_out(const float* __restrict__ Hst,
                                                const float* __restrict__ Wout,  // [H,V]
                                                const float* __restrict__ bout,
                                                int step,
                                                float* __restrict__ seqO,
                                                float* __restrict__ logO,
                                                float* __restrict__ entO,
                                                float* __restrict__ lenO,
                                                int* __restrict__ symO) {
    __shared__ float lds[64 * 128];                     // 32 KiB, unioned
    float (*As)[68]  = (float (*)[68])lds;              // [16][68] transposed A (padded)
    float (*Bs)[128] = (float (*)[128])(lds + 16 * 68); // [16][128]
    float (*Ct)[128] = (float (*)[128])lds;             // [64][128] epilogue tile

    const int tid = threadIdx.x;
    const int tx = tid & 15, ty = tid >> 4;
    const int r0 = blockIdx.x * 64;

    const int arow = tid >> 2;         // 0..63
    const int acol = (tid & 3) * 4;
    const int bk   = tid >> 5;         // 0..7 (+8 for second load)
    const int bcol = (tid & 31) * 4;

    const float* Abase = Hst + r0 * Hdim;
    float acc[4][8] = {};

    float4 pa  = *(const float4*)(Abase + arow * Hdim + acol);
    float4 pb0 = *(const float4*)(Wout + bk * Vdim + bcol);
    float4 pb1 = *(const float4*)(Wout + (bk + 8) * Vdim + bcol);

    for (int kc = 0; kc < Hdim / 16; ++kc) {
        __syncthreads();
        As[acol + 0][arow] = pa.x;  As[acol + 1][arow] = pa.y;
        As[acol + 2][arow] = pa.z;  As[acol + 3][arow] = pa.w;
        *(float4*)&Bs[bk][bcol]     = pb0;
        *(float4*)&Bs[bk + 8][bcol] = pb1;
        __syncthreads();
        if (kc + 1 < Hdim / 16) {
            const int k0 = (kc + 1) * 16;
            pa  = *(const float4*)(Abase + arow * Hdim + k0 + acol);
            pb0 = *(const float4*)(Wout + (k0 + bk) * Vdim + bcol);
            pb1 = *(const float4*)(Wout + (k0 + bk + 8) * Vdim + bcol);
        }
        #pragma unroll
        for (int k = 0; k < 16; ++k) {
            const float4 a  = *(const float4*)&As[k][ty * 4];
            const float4 b0 = *(const float4*)&Bs[k][tx * 4];
            const float4 b1 = *(const float4*)&Bs[k][64 + tx * 4];
            const float av[4] = {a.x, a.y, a.z, a.w};
            const float bv[8] = {b0.x,b0.y,b0.z,b0.w,b1.x,b1.y,b1.z,b1.w};
            #pragma unroll
            for (int i = 0; i < 4; ++i)
                #pragma unroll
                for (int n = 0; n < 8; ++n)
                    acc[i][n] = fmaf(av[i], bv[n], acc[i][n]);
        }
    }

    __syncthreads();
    const float4 bo0 = *(const float4*)(bout + tx * 4);
    const float4 bo1 = *(const float4*)(bout + 64 + tx * 4);
    #pragma unroll
    for (int i = 0; i < 4; ++i) {
        float4 c0v, c1v;
        c0v.x = acc[i][0] + bo0.x;  c0v.y = acc[i][1] + bo0.y;
        c0v.z = acc[i][2] + bo0.z;  c0v.w = acc[i][3] + bo0.w;
        c1v.x = acc[i][4] + bo1.x;  c1v.y = acc[i][5] + bo1.y;
        c1v.z = acc[i][6] + bo1.z;  c1v.w = acc[i][7] + bo1.w;
        *(float4*)&Ct[ty * 4 + i][tx * 4]      = c0v;
        *(float4*)&Ct[ty * 4 + i][64 + tx * 4] = c1v;
    }
    __syncthreads();

    // one wave per row: max/argmax (first-index ties), logsumexp, entropy
    const int wid = tid >> 6, lane = tid & 63;
    for (int r = wid; r < 64; r += 4) {
        const float v0 = Ct[r][lane];
        const float v1 = Ct[r][lane + 64];
        float bv = v0; int bi = lane;
        if (v1 > bv) { bv = v1; bi = lane + 64; }
        #pragma unroll
        for (int off = 32; off > 0; off >>= 1) {
            const float ov = __shfl_down(bv, off);
            const int   oi = __shfl_down(bi, off);
            if (ov > bv || (ov == bv && oi < bi)) { bv = ov; bi = oi; }
        }
        const float m  = __shfl(bv, 0);
        const int   am = __shfl(bi, 0);
        const float e0 = __expf(v0 - m), e1 = __expf(v1 - m);
        float s  = e0 + e1;
        float t2 = fmaf(e0, v0 - m, e1 * (v1 - m));
        #pragma unroll
        for (int off = 1; off < 64; off <<= 1) {
            s  += __shfl_xor(s, off);
            t2 += __shfl_xor(t2, off);
        }
        if (lane == 0) {
            const float logS = logf(s);
            const float ent  = logS - t2 / s;        // = -sum p*logp
            const int rg = r0 + r;
            seqO[rg * Lmsg + step] = (float)am;
            logO[rg * Lmsg + step] = -logS;          // logp at the argmax
            symO[rg] = am;
            if (step == 0) { entO[rg] = ent * (1.0f / Lmsg); lenO[rg] = (float)Lmsg; }
            else           { entO[rg] += ent * (1.0f / Lmsg); }
        }
    }
}

} // namespace

extern "C" void kernel_launch(void* const* d_in, const int* in_sizes, int n_in,
                              void* d_out, int out_size, void* d_ws, size_t ws_size,
                              hipStream_t stream) {
    (void)in_sizes; (void)n_in; (void)out_size; (void)ws_size;

    const float* inputs = (const float*)d_in[0];
    const float* W_vh   = (const float*)d_in[1];
    const float* b_vh   = (const float*)d_in[2];
    const float* gk     = (const float*)d_in[3];
    const float* guk    = (const float*)d_in[4];
    const float* gbias  = (const float*)d_in[5];   // [2][3H]
    const float* Wout   = (const float*)d_in[6];
    const float* bout   = (const float*)d_in[7];
    const float* emb    = (const float*)d_in[8];

    float* out  = (float*)d_out;
    float* seqO = out;
    float* logO = out + (size_t)Bsz * Lmsg;
    float* entO = out + (size_t)2 * Bsz * Lmsg;
    float* lenO = entO + Bsz;
    float* hA   = lenO + Bsz;                       // [B,H]: final h_t lives here

    float* ws    = (float*)d_ws;
    float* hB    = ws;                              // [B,H] double buffer
    float* emb_k = ws + (size_t)Bsz * Hdim;         // [V,3H]
    int*   sym   = (int*)(emb_k + (size_t)Vdim * H3);

    const float* bias0 = gbias;

    k_embk<<<dim3(Vdim * H3 / 256), 256, 0, stream>>>(emb, gk, bias0, emb_k, sym);
    k_vision<<<dim3(Hdim / 64, Bsz / 128), 256, 0, stream>>>(inputs, W_vh, b_vh, hA);

    for (int t = 0; t < Lmsg; ++t) {
        float* hc = (t & 1) ? hB : hA;   // h0 in hA; h10 lands back in hA (out)
        float* hn = (t & 1) ? hA : hB;
        k_gru<<<dim3(Hdim / 64, Bsz / 128), 256, 0, stream>>>(hc, guk, gbias, emb_k, sym, t, hn);
        k_out<<<dim3(Bsz / 64), 256, 0, stream>>>(hn, Wout, bout, t, seqO, logO, entO, lenO, sym);
    }
}

// Round 5
// 1835.065 us; speedup vs baseline: 2.2598x; 2.2598x over previous
//
#include <hip/hip_runtime.h>
#include <math.h>

namespace {

constexpr int Bsz  = 16384;
constexpr int Fdim = 512;
constexpr int Hdim = 512;
constexpr int Vdim = 128;
constexpr int Lmsg = 10;
constexpr int H3   = 3 * Hdim;   // 1536

// f16 split scale: h = hi + lo/32 ; U = Uhi + Ulo/32
// GEMM terms: hi*Uhi + (hi/32)*(Ulo*32) + (lo*32)*(Uhi/32)  -- scales cancel
// per product, so all three MFMAs share one fp32 accumulator.
constexpr float SPLIT_SC  = 32.0f;
constexpr float SPLIT_INV = 0.03125f;

typedef _Float16 half4v __attribute__((ext_vector_type(4)));
typedef _Float16 half8v __attribute__((ext_vector_type(8)));
typedef float    f32x4  __attribute__((ext_vector_type(4)));

__device__ __forceinline__ float sigm(float x) { return 1.0f / (1.0f + __expf(-x)); }

// ---------------------------------------------------------------------------
// emb_k[v][j] = sum_e embedding[v][e] * gru_kernel[e][j] + bias0[j]  (fp32)
// ---------------------------------------------------------------------------
__global__ void k_embk(const float* __restrict__ emb, const float* __restrict__ gk,
                       const float* __restrict__ bias0, float* __restrict__ emb_k,
                       int* __restrict__ sym) {
    const int gid = blockIdx.x * 256 + threadIdx.x;       // V*H3 = 196608 threads
    const int v = gid / H3, j = gid - v * H3;
    float acc = bias0[j];
    const float* er = emb + v * 128;
    #pragma unroll 4
    for (int e = 0; e < 128; ++e) acc = fmaf(er[e], gk[e * H3 + j], acc);
    emb_k[gid] = acc;
    if (gid < Bsz) sym[gid] = 0;
}

// ---------------------------------------------------------------------------
// U split+transpose: Ut_hi/Ut_lo [1536][512] f16 from guk fp32 [512][1536]
// ---------------------------------------------------------------------------
__global__ void k_usplit(const float* __restrict__ guk,
                         _Float16* __restrict__ uthi, _Float16* __restrict__ utlo) {
    const int gid = blockIdx.x * 256 + threadIdx.x;  // 1536*512 = 786432
    const int j = gid >> 9, k = gid & 511;
    const float u = guk[(size_t)k * H3 + j];
    const _Float16 hi = (_Float16)u;
    uthi[gid] = hi;                                   // [j][k]
    utlo[gid] = (_Float16)((u - (float)hi) * SPLIT_SC);
}

// ---------------------------------------------------------------------------
// h0 = tanh(inputs @ W_vh + b_vh) -> f16 hi/lo planes
// BM=128, BN=64, BK=16, 256 threads, each 8x4 outputs. (fp32 VALU)
// ---------------------------------------------------------------------------
__global__ __launch_bounds__(256, 2) void k_vision(const float* __restrict__ A,
                                                   const float* __restrict__ W,
                                                   const float* __restrict__ bias,
                                                   _Float16* __restrict__ hiP,
                                                   _Float16* __restrict__ loP) {
    __shared__ float As[16][132];   // transposed A tile (padded)
    __shared__ float Bs[16][64];
    const int tid = threadIdx.x;
    const int tx = tid & 15, ty = tid >> 4;
    const int r0 = blockIdx.y * 128, c0 = blockIdx.x * 64;

    const int arow = tid >> 2;
    const int acol = (tid & 3) * 4;
    const int bk   = tid >> 4;
    const int bcol = (tid & 15) * 4;

    const float* Abase = A + r0 * Fdim;
    float acc[8][4] = {};

    float4 pa0 = *(const float4*)(Abase + arow * Fdim + acol);
    float4 pa1 = *(const float4*)(Abase + (arow + 64) * Fdim + acol);
    float4 pb  = *(const float4*)(W + bk * Hdim + c0 + bcol);

    for (int kc = 0; kc < Fdim / 16; ++kc) {
        __syncthreads();
        As[acol + 0][arow] = pa0.x;  As[acol + 1][arow] = pa0.y;
        As[acol + 2][arow] = pa0.z;  As[acol + 3][arow] = pa0.w;
        As[acol + 0][arow + 64] = pa1.x;  As[acol + 1][arow + 64] = pa1.y;
        As[acol + 2][arow + 64] = pa1.z;  As[acol + 3][arow + 64] = pa1.w;
        *(float4*)&Bs[bk][bcol] = pb;
        __syncthreads();
        if (kc + 1 < Fdim / 16) {
            const int k0 = (kc + 1) * 16;
            pa0 = *(const float4*)(Abase + arow * Fdim + k0 + acol);
            pa1 = *(const float4*)(Abase + (arow + 64) * Fdim + k0 + acol);
            pb  = *(const float4*)(W + (k0 + bk) * Hdim + c0 + bcol);
        }
        #pragma unroll
        for (int k = 0; k < 16; ++k) {
            const float4 a0 = *(const float4*)&As[k][ty * 8];
            const float4 a1 = *(const float4*)&As[k][ty * 8 + 4];
            const float4 b  = *(const float4*)&Bs[k][tx * 4];
            const float av[8] = {a0.x,a0.y,a0.z,a0.w,a1.x,a1.y,a1.z,a1.w};
            const float bv[4] = {b.x,b.y,b.z,b.w};
            #pragma unroll
            for (int i = 0; i < 8; ++i)
                #pragma unroll
                for (int n = 0; n < 4; ++n)
                    acc[i][n] = fmaf(av[i], bv[n], acc[i][n]);
        }
    }
    const float4 bb = *(const float4*)(bias + c0 + tx * 4);
    #pragma unroll
    for (int i = 0; i < 8; ++i) {
        const int r = r0 + ty * 8 + i;
        float o0 = tanhf(acc[i][0] + bb.x);
        float o1 = tanhf(acc[i][1] + bb.y);
        float o2 = tanhf(acc[i][2] + bb.z);
        float o3 = tanhf(acc[i][3] + bb.w);
        half4v hv, lv;
        hv.x = (_Float16)o0; lv.x = (_Float16)((o0 - (float)hv.x) * SPLIT_SC);
        hv.y = (_Float16)o1; lv.y = (_Float16)((o1 - (float)hv.y) * SPLIT_SC);
        hv.z = (_Float16)o2; lv.z = (_Float16)((o2 - (float)hv.z) * SPLIT_SC);
        hv.w = (_Float16)o3; lv.w = (_Float16)((o3 - (float)hv.w) * SPLIT_SC);
        *(half4v*)(hiP + (size_t)r * Hdim + c0 + tx * 4) = hv;
        *(half4v*)(loP + (size_t)r * Hdim + c0 + tx * 4) = lv;
    }
}

// ---------------------------------------------------------------------------
// MFMA GRU step. Tile: 128 rows x 32 cols x 3 gates, BK=32, 4 waves.
// Wave w owns rows [w*32, +32). LDS: double-buffered, per buffer:
//   Ahi 0..8191, Alo 8192..16383, Bhi 16384..22527, Blo 22528..28671
// LDS rows are 64B (32 f16); element (r,k) stored at slot (k>>3)^(r&3)
// (XOR swizzle, realized by pre-swizzled per-lane global source since
//  global_load_lds writes linearly; read applies the same involution).
// ---------------------------------------------------------------------------
__global__ __launch_bounds__(256, 2) void k_gru(
    const _Float16* __restrict__ hiIn, const _Float16* __restrict__ loIn,
    const _Float16* __restrict__ uthi, const _Float16* __restrict__ utlo,
    const float* __restrict__ gbias,   // [2][1536]
    const float* __restrict__ emb_k,   // [128][1536] (includes bias0)
    const int* __restrict__ sym,
    int step,
    _Float16* __restrict__ hiOut, _Float16* __restrict__ loOut,
    float* __restrict__ hF) {          // non-null on last step: f32 h_t out

    __shared__ __align__(16) char smem[2 * 28672];
    const int tid = threadIdx.x;
    const int l = tid & 63, w = tid >> 6;

    // XCD-aware swizzle: 2048 blocks = 8 XCDs x 256; 16 consecutive swz share
    // a row-panel (A reuse in the XCD's L2).
    const int bid = blockIdx.x;
    const int swz = (bid & 7) * 256 + (bid >> 3);
    const int rb = swz >> 4, cb = swz & 15;
    const int m0 = rb * 128, c0 = cb * 32;

    // ---- staging tables: 7 global_load_lds segments per wave ----
    const char* gsrc[7];
    int loff[7];
    {
        int n = 0;
        #pragma unroll
        for (int s0 = 0; s0 < 4; ++s0) {        // A segs: s = w + s0*4 in [0,16)
            const int s = w + s0 * 4;
            const _Float16* pl = (s < 8) ? hiIn : loIn;
            const int seg = (s < 8) ? s : s - 8;
            const int grow = seg * 16 + (l >> 2);
            const int slot = (l & 3) ^ (grow & 3);
            gsrc[n] = (const char*)(pl + (size_t)(m0 + grow) * Hdim) + slot * 16;
            loff[n] = ((s < 8) ? 0 : 8192) + seg * 1024;
            ++n;
        }
        #pragma unroll
        for (int s0 = 0; s0 < 3; ++s0) {        // B segs: s = w + s0*4 in [0,12)
            const int s = w + s0 * 4;
            const _Float16* pl = (s < 6) ? uthi : utlo;
            const int seg = (s < 6) ? s : s - 6;
            const int jrow = seg * 16 + (l >> 2);
            const int g = jrow >> 5, jl = jrow & 31;
            const int slot = (l & 3) ^ (jrow & 3);
            gsrc[n] = (const char*)(pl + (size_t)(g * Hdim + c0 + jl) * Hdim) + slot * 16;
            loff[n] = 16384 + ((s < 6) ? 0 : 6144) + seg * 1024;
            ++n;
        }
    }

    f32x4 acc[2][2][3] = {};   // [mf][nf][gate]

    // prologue stage chunk 0 into buffer 0
    {
        char* lb = smem;
        #pragma unroll
        for (int i = 0; i < 7; ++i)
            __builtin_amdgcn_global_load_lds(
                (const __attribute__((address_space(1))) void*)(gsrc[i]),
                (__attribute__((address_space(3))) void*)(lb + loff[i]), 16, 0, 0);
    }

    const int fr = l & 15;                 // fragment row/col index
    const int kb_lane = l >> 4;            // k-block 0..3
    const int sw_rd = ((kb_lane ^ (l & 3)) << 4);

    for (int kc = 0; kc < 16; ++kc) {
        __syncthreads();                   // drains vm+lgkm: buf[kc&1] ready
        if (kc < 15) {
            char* lb = smem + ((kc + 1) & 1) * 28672;
            const int kbyt = (kc + 1) * 64;
            #pragma unroll
            for (int i = 0; i < 7; ++i)
                __builtin_amdgcn_global_load_lds(
                    (const __attribute__((address_space(1))) void*)(gsrc[i] + kbyt),
                    (__attribute__((address_space(3))) void*)(lb + loff[i]), 16, 0, 0);
        }
        const char* lb = smem + (kc & 1) * 28672;

        half8v ahi[2], alo[2], ahid[2];
        #pragma unroll
        for (int mf = 0; mf < 2; ++mf) {
            const int r = w * 32 + mf * 16 + fr;
            const int byt = r * 64 + sw_rd;
            ahi[mf]  = *(const half8v*)(lb + byt);
            alo[mf]  = *(const half8v*)(lb + 8192 + byt);
            ahid[mf] = ahi[mf] * (_Float16)SPLIT_INV;
        }
        #pragma unroll
        for (int g = 0; g < 3; ++g) {
            #pragma unroll
            for (int nf = 0; nf < 2; ++nf) {
                const int jrow = g * 32 + nf * 16 + fr;
                const int byt = jrow * 64 + sw_rd;
                half8v bhi  = *(const half8v*)(lb + 16384 + byt);
                half8v blo  = *(const half8v*)(lb + 22528 + byt);
                half8v bhid = bhi * (_Float16)SPLIT_INV;
                #pragma unroll
                for (int mf = 0; mf < 2; ++mf) {
                    acc[mf][nf][g] = __builtin_amdgcn_mfma_f32_16x16x32_f16(
                        ahi[mf], bhi, acc[mf][nf][g], 0, 0, 0);
                    acc[mf][nf][g] = __builtin_amdgcn_mfma_f32_16x16x32_f16(
                        ahid[mf], blo, acc[mf][nf][g], 0, 0, 0);
                    acc[mf][nf][g] = __builtin_amdgcn_mfma_f32_16x16x32_f16(
                        alo[mf], bhid, acc[mf][nf][g], 0, 0, 0);
                }
            }
        }
    }

    // ---- GRU cell epilogue ----
    const float* bias1 = gbias + H3;
    float b1z[2], b1r[2], b1h[2];
    #pragma unroll
    for (int nf = 0; nf < 2; ++nf) {
        const int jg = c0 + nf * 16 + fr;
        b1z[nf] = bias1[jg];
        b1r[nf] = bias1[Hdim + jg];
        b1h[nf] = bias1[2 * Hdim + jg];
    }
    #pragma unroll
    for (int mf = 0; mf < 2; ++mf) {
        #pragma unroll
        for (int q = 0; q < 4; ++q) {
            const int r = m0 + w * 32 + mf * 16 + kb_lane * 4 + q;
            const float* xrow = (step == 0) ? gbias : (emb_k + (size_t)sym[r] * H3);
            #pragma unroll
            for (int nf = 0; nf < 2; ++nf) {
                const int jg = c0 + nf * 16 + fr;
                const float xz = xrow[jg];
                const float xr_ = xrow[Hdim + jg];
                const float xh = xrow[2 * Hdim + jg];
                const float az = acc[mf][nf][0][q];
                const float ar = acc[mf][nf][1][q];
                const float ah = acc[mf][nf][2][q];
                const size_t idx = (size_t)r * Hdim + jg;
                const float hold = (float)hiIn[idx] + (float)loIn[idx] * SPLIT_INV;
                const float z  = sigm(xz + b1z[nf] + az);
                const float rr = sigm(xr_ + b1r[nf] + ar);
                const float hh = tanhf(xh + rr * (b1h[nf] + ah));
                const float o = z * hold + (1.0f - z) * hh;
                const _Float16 oh = (_Float16)o;
                hiOut[idx] = oh;
                loOut[idx] = (_Float16)((o - (float)oh) * SPLIT_SC);
                if (hF) hF[idx] = o;
            }
        }
    }
}

// ---------------------------------------------------------------------------
// Output head (fp32 VALU, precision-critical): logits = h @ W_out + b_out,
// fused log-softmax / entropy / argmax. h reconstructed from f16 hi/lo.
// ---------------------------------------------------------------------------
__global__ __launch_bounds__(256, 2) void k_out(const _Float16* __restrict__ hiP,
                                                const _Float16* __restrict__ loP,
                                                const float* __restrict__ Wout,  // [H,V]
                                                const float* __restrict__ bout,
                                                int step,
                                                float* __restrict__ seqO,
                                                float* __restrict__ logO,
                                                float* __restrict__ entO,
                                                float* __restrict__ lenO,
                                                int* __restrict__ symO) {
    __shared__ float lds[64 * 128];
    float (*As)[68]  = (float (*)[68])lds;              // [16][68] transposed A (padded)
    float (*Bs)[128] = (float (*)[128])(lds + 16 * 68); // [16][128]
    float (*Ct)[128] = (float (*)[128])lds;             // [64][128] epilogue tile

    const int tid = threadIdx.x;
    const int tx = tid & 15, ty = tid >> 4;
    const int r0 = blockIdx.x * 64;

    const int arow = tid >> 2;
    const int acol = (tid & 3) * 4;
    const int bk   = tid >> 5;
    const int bcol = (tid & 31) * 4;

    const size_t abase = (size_t)(r0 + arow) * Hdim;
    float acc[4][8] = {};

    half4v pha = *(const half4v*)(hiP + abase + acol);
    half4v pla = *(const half4v*)(loP + abase + acol);
    float4 pb0 = *(const float4*)(Wout + bk * Vdim + bcol);
    float4 pb1 = *(const float4*)(Wout + (bk + 8) * Vdim + bcol);

    for (int kc = 0; kc < Hdim / 16; ++kc) {
        __syncthreads();
        As[acol + 0][arow] = (float)pha.x + (float)pla.x * SPLIT_INV;
        As[acol + 1][arow] = (float)pha.y + (float)pla.y * SPLIT_INV;
        As[acol + 2][arow] = (float)pha.z + (float)pla.z * SPLIT_INV;
        As[acol + 3][arow] = (float)pha.w + (float)pla.w * SPLIT_INV;
        *(float4*)&Bs[bk][bcol]     = pb0;
        *(float4*)&Bs[bk + 8][bcol] = pb1;
        __syncthreads();
        if (kc + 1 < Hdim / 16) {
            const int k0 = (kc + 1) * 16;
            pha = *(const half4v*)(hiP + abase + k0 + acol);
            pla = *(const half4v*)(loP + abase + k0 + acol);
            pb0 = *(const float4*)(Wout + (k0 + bk) * Vdim + bcol);
            pb1 = *(const float4*)(Wout + (k0 + bk + 8) * Vdim + bcol);
        }
        #pragma unroll
        for (int k = 0; k < 16; ++k) {
            const float4 a  = *(const float4*)&As[k][ty * 4];
            const float4 b0 = *(const float4*)&Bs[k][tx * 4];
            const float4 b1 = *(const float4*)&Bs[k][64 + tx * 4];
            const float av[4] = {a.x, a.y, a.z, a.w};
            const float bv[8] = {b0.x,b0.y,b0.z,b0.w,b1.x,b1.y,b1.z,b1.w};
            #pragma unroll
            for (int i = 0; i < 4; ++i)
                #pragma unroll
                for (int n = 0; n < 8; ++n)
                    acc[i][n] = fmaf(av[i], bv[n], acc[i][n]);
        }
    }

    __syncthreads();
    const float4 bo0 = *(const float4*)(bout + tx * 4);
    const float4 bo1 = *(const float4*)(bout + 64 + tx * 4);
    #pragma unroll
    for (int i = 0; i < 4; ++i) {
        float4 c0v, c1v;
        c0v.x = acc[i][0] + bo0.x;  c0v.y = acc[i][1] + bo0.y;
        c0v.z = acc[i][2] + bo0.z;  c0v.w = acc[i][3] + bo0.w;
        c1v.x = acc[i][4] + bo1.x;  c1v.y = acc[i][5] + bo1.y;
        c1v.z = acc[i][6] + bo1.z;  c1v.w = acc[i][7] + bo1.w;
        *(float4*)&Ct[ty * 4 + i][tx * 4]      = c0v;
        *(float4*)&Ct[ty * 4 + i][64 + tx * 4] = c1v;
    }
    __syncthreads();

    const int wid = tid >> 6, lane = tid & 63;
    for (int r = wid; r < 64; r += 4) {
        const float v0 = Ct[r][lane];
        const float v1 = Ct[r][lane + 64];
        float bv = v0; int bi = lane;
        if (v1 > bv) { bv = v1; bi = lane + 64; }
        #pragma unroll
        for (int off = 32; off > 0; off >>= 1) {
            const float ov = __shfl_down(bv, off);
            const int   oi = __shfl_down(bi, off);
            if (ov > bv || (ov == bv && oi < bi)) { bv = ov; bi = oi; }
        }
        const float m  = __shfl(bv, 0);
        const int   am = __shfl(bi, 0);
        const float e0 = __expf(v0 - m), e1 = __expf(v1 - m);
        float s  = e0 + e1;
        float t2 = fmaf(e0, v0 - m, e1 * (v1 - m));
        #pragma unroll
        for (int off = 1; off < 64; off <<= 1) {
            s  += __shfl_xor(s, off);
            t2 += __shfl_xor(t2, off);
        }
        if (lane == 0) {
            const float logS = logf(s);
            const float ent  = logS - t2 / s;
            const int rg = r0 + r;
            seqO[rg * Lmsg + step] = (float)am;
            logO[rg * Lmsg + step] = -logS;
            symO[rg] = am;
            if (step == 0) { entO[rg] = ent * (1.0f / Lmsg); lenO[rg] = (float)Lmsg; }
            else           { entO[rg] += ent * (1.0f / Lmsg); }
        }
    }
}

} // namespace

extern "C" void kernel_launch(void* const* d_in, const int* in_sizes, int n_in,
                              void* d_out, int out_size, void* d_ws, size_t ws_size,
                              hipStream_t stream) {
    (void)in_sizes; (void)n_in; (void)out_size; (void)ws_size;

    const float* inputs = (const float*)d_in[0];
    const float* W_vh   = (const float*)d_in[1];
    const float* b_vh   = (const float*)d_in[2];
    const float* gk     = (const float*)d_in[3];
    const float* guk    = (const float*)d_in[4];
    const float* gbias  = (const float*)d_in[5];   // [2][3H]
    const float* Wout   = (const float*)d_in[6];
    const float* bout   = (const float*)d_in[7];
    const float* emb    = (const float*)d_in[8];

    float* out  = (float*)d_out;
    float* seqO = out;
    float* logO = out + (size_t)Bsz * Lmsg;
    float* entO = out + (size_t)2 * Bsz * Lmsg;
    float* lenO = entO + Bsz;
    float* hF   = lenO + Bsz;                       // [B,H] f32 final h_t

    char* wsb = (char*)d_ws;
    const size_t PLANE = (size_t)Bsz * Hdim * sizeof(_Float16);  // 16 MiB
    _Float16* pH[2] = { (_Float16*)(wsb),             (_Float16*)(wsb + 2 * PLANE) };
    _Float16* pL[2] = { (_Float16*)(wsb + PLANE),     (_Float16*)(wsb + 3 * PLANE) };
    _Float16* uthi  = (_Float16*)(wsb + 4 * PLANE);
    _Float16* utlo  = (_Float16*)(wsb + 4 * PLANE + (size_t)H3 * Hdim * sizeof(_Float16));
    float*    emb_k = (float*)   (wsb + 4 * PLANE + (size_t)2 * H3 * Hdim * sizeof(_Float16));
    int*      sym   = (int*)     ((char*)emb_k + (size_t)Vdim * H3 * sizeof(float));

    k_embk  <<<dim3(Vdim * H3 / 256), 256, 0, stream>>>(emb, gk, gbias, emb_k, sym);
    k_usplit<<<dim3(H3 * Hdim / 256), 256, 0, stream>>>(guk, uthi, utlo);
    k_vision<<<dim3(Hdim / 64, Bsz / 128), 256, 0, stream>>>(inputs, W_vh, b_vh, pH[0], pL[0]);

    for (int t = 0; t < Lmsg; ++t) {
        const int rd = t & 1, wr = (t + 1) & 1;
        k_gru<<<dim3((Bsz / 128) * (Hdim / 32)), 256, 0, stream>>>(
            pH[rd], pL[rd], uthi, utlo, gbias, emb_k, sym, t,
            pH[wr], pL[wr], (t == Lmsg - 1) ? hF : nullptr);
        k_out<<<dim3(Bsz / 64), 256, 0, stream>>>(
            pH[wr], pL[wr], Wout, bout, t, seqO, logO, entO, lenO, sym);
    }
}

// Round 6
// 1497.323 us; speedup vs baseline: 2.7695x; 1.2256x over previous
//
#include <hip/hip_runtime.h>
#include <math.h>

namespace {

constexpr int Bsz  = 16384;
constexpr int Fdim = 512;
constexpr int Hdim = 512;
constexpr int Vdim = 128;
constexpr int Lmsg = 10;
constexpr int H3   = 3 * Hdim;   // 1536

// f16 split scale: h = hi + lo/32 ; U = Uhi + Ulo/32
// GEMM terms: hi*Uhi + (hi/32)*(Ulo*32) + (lo*32)*(Uhi/32)  -- scales cancel
// per product, so all three MFMAs share one fp32 accumulator.
constexpr float SPLIT_SC  = 32.0f;
constexpr float SPLIT_INV = 0.03125f;

typedef _Float16 half4v __attribute__((ext_vector_type(4)));
typedef _Float16 half8v __attribute__((ext_vector_type(8)));
typedef float    f32x4  __attribute__((ext_vector_type(4)));

__device__ __forceinline__ float sigm(float x) { return 1.0f / (1.0f + __expf(-x)); }

// ---------------------------------------------------------------------------
// emb_k[v][j] = sum_e embedding[v][e] * gru_kernel[e][j] + bias0[j]  (fp32)
// ---------------------------------------------------------------------------
__global__ void k_embk(const float* __restrict__ emb, const float* __restrict__ gk,
                       const float* __restrict__ bias0, float* __restrict__ emb_k,
                       int* __restrict__ sym) {
    const int gid = blockIdx.x * 256 + threadIdx.x;       // V*H3 = 196608 threads
    const int v = gid / H3, j = gid - v * H3;
    float acc = bias0[j];
    const float* er = emb + v * 128;
    #pragma unroll 4
    for (int e = 0; e < 128; ++e) acc = fmaf(er[e], gk[e * H3 + j], acc);
    emb_k[gid] = acc;
    if (gid < Bsz) sym[gid] = 0;
}

// ---------------------------------------------------------------------------
// U split+transpose: Ut_hi/Ut_lo [1536][512] f16 from guk fp32 [512][1536]
// ---------------------------------------------------------------------------
__global__ void k_usplit(const float* __restrict__ guk,
                         _Float16* __restrict__ uthi, _Float16* __restrict__ utlo) {
    const int gid = blockIdx.x * 256 + threadIdx.x;  // 1536*512 = 786432
    const int j = gid >> 9, k = gid & 511;
    const float u = guk[(size_t)k * H3 + j];
    const _Float16 hi = (_Float16)u;
    uthi[gid] = hi;                                   // [j][k]
    utlo[gid] = (_Float16)((u - (float)hi) * SPLIT_SC);
}

// ---------------------------------------------------------------------------
// Wout split+transpose: [512,128] fp32 -> wt_hi/wt_lo [128][512] f16
// ---------------------------------------------------------------------------
__global__ void k_osplit(const float* __restrict__ Wout,
                         _Float16* __restrict__ wthi, _Float16* __restrict__ wtlo) {
    const int gid = blockIdx.x * 256 + threadIdx.x;  // 128*512 = 65536
    const int j = gid >> 9, k = gid & 511;           // j: out col, k: h dim
    const float u = Wout[(size_t)k * Vdim + j];
    const _Float16 hi = (_Float16)u;
    wthi[gid] = hi;                                   // [j][k]
    wtlo[gid] = (_Float16)((u - (float)hi) * SPLIT_SC);
}

// ---------------------------------------------------------------------------
// h0 = tanh(inputs @ W_vh + b_vh) -> f16 hi/lo planes
// BM=128, BN=64, BK=16, 256 threads, each 8x4 outputs. (fp32 VALU)
// ---------------------------------------------------------------------------
__global__ __launch_bounds__(256, 2) void k_vision(const float* __restrict__ A,
                                                   const float* __restrict__ W,
                                                   const float* __restrict__ bias,
                                                   _Float16* __restrict__ hiP,
                                                   _Float16* __restrict__ loP) {
    __shared__ float As[16][132];   // transposed A tile (padded)
    __shared__ float Bs[16][64];
    const int tid = threadIdx.x;
    const int tx = tid & 15, ty = tid >> 4;
    const int r0 = blockIdx.y * 128, c0 = blockIdx.x * 64;

    const int arow = tid >> 2;
    const int acol = (tid & 3) * 4;
    const int bk   = tid >> 4;
    const int bcol = (tid & 15) * 4;

    const float* Abase = A + r0 * Fdim;
    float acc[8][4] = {};

    float4 pa0 = *(const float4*)(Abase + arow * Fdim + acol);
    float4 pa1 = *(const float4*)(Abase + (arow + 64) * Fdim + acol);
    float4 pb  = *(const float4*)(W + bk * Hdim + c0 + bcol);

    for (int kc = 0; kc < Fdim / 16; ++kc) {
        __syncthreads();
        As[acol + 0][arow] = pa0.x;  As[acol + 1][arow] = pa0.y;
        As[acol + 2][arow] = pa0.z;  As[acol + 3][arow] = pa0.w;
        As[acol + 0][arow + 64] = pa1.x;  As[acol + 1][arow + 64] = pa1.y;
        As[acol + 2][arow + 64] = pa1.z;  As[acol + 3][arow + 64] = pa1.w;
        *(float4*)&Bs[bk][bcol] = pb;
        __syncthreads();
        if (kc + 1 < Fdim / 16) {
            const int k0 = (kc + 1) * 16;
            pa0 = *(const float4*)(Abase + arow * Fdim + k0 + acol);
            pa1 = *(const float4*)(Abase + (arow + 64) * Fdim + k0 + acol);
            pb  = *(const float4*)(W + (k0 + bk) * Hdim + c0 + bcol);
        }
        #pragma unroll
        for (int k = 0; k < 16; ++k) {
            const float4 a0 = *(const float4*)&As[k][ty * 8];
            const float4 a1 = *(const float4*)&As[k][ty * 8 + 4];
            const float4 b  = *(const float4*)&Bs[k][tx * 4];
            const float av[8] = {a0.x,a0.y,a0.z,a0.w,a1.x,a1.y,a1.z,a1.w};
            const float bv[4] = {b.x,b.y,b.z,b.w};
            #pragma unroll
            for (int i = 0; i < 8; ++i)
                #pragma unroll
                for (int n = 0; n < 4; ++n)
                    acc[i][n] = fmaf(av[i], bv[n], acc[i][n]);
        }
    }
    const float4 bb = *(const float4*)(bias + c0 + tx * 4);
    #pragma unroll
    for (int i = 0; i < 8; ++i) {
        const int r = r0 + ty * 8 + i;
        float o0 = tanhf(acc[i][0] + bb.x);
        float o1 = tanhf(acc[i][1] + bb.y);
        float o2 = tanhf(acc[i][2] + bb.z);
        float o3 = tanhf(acc[i][3] + bb.w);
        half4v hv, lv;
        hv.x = (_Float16)o0; lv.x = (_Float16)((o0 - (float)hv.x) * SPLIT_SC);
        hv.y = (_Float16)o1; lv.y = (_Float16)((o1 - (float)hv.y) * SPLIT_SC);
        hv.z = (_Float16)o2; lv.z = (_Float16)((o2 - (float)hv.z) * SPLIT_SC);
        hv.w = (_Float16)o3; lv.w = (_Float16)((o3 - (float)hv.w) * SPLIT_SC);
        *(half4v*)(hiP + (size_t)r * Hdim + c0 + tx * 4) = hv;
        *(half4v*)(loP + (size_t)r * Hdim + c0 + tx * 4) = lv;
    }
}

// ---------------------------------------------------------------------------
// MFMA GRU step. Tile: 128 rows x 32 cols x 3 gates, BK=32, 4 waves.
// Wave w owns rows [w*32, +32). LDS: double-buffered, per buffer:
//   Ahi 0..8191, Alo 8192..16383, Bhi 16384..22527, Blo 22528..28671
// LDS rows are 64B (32 f16); element (r,k) stored at slot (k>>3)^(r&3)
// (XOR swizzle, realized by pre-swizzled per-lane global source since
//  global_load_lds writes linearly; read applies the same involution).
// ---------------------------------------------------------------------------
__global__ __launch_bounds__(256, 2) void k_gru(
    const _Float16* __restrict__ hiIn, const _Float16* __restrict__ loIn,
    const _Float16* __restrict__ uthi, const _Float16* __restrict__ utlo,
    const float* __restrict__ gbias,   // [2][1536]
    const float* __restrict__ emb_k,   // [128][1536] (includes bias0)
    const int* __restrict__ sym,
    int step,
    _Float16* __restrict__ hiOut, _Float16* __restrict__ loOut,
    float* __restrict__ hF) {          // non-null on last step: f32 h_t out

    __shared__ __align__(16) char smem[2 * 28672];
    const int tid = threadIdx.x;
    const int l = tid & 63, w = tid >> 6;

    // XCD-aware swizzle: 2048 blocks = 8 XCDs x 256; 16 consecutive swz share
    // a row-panel (A reuse in the XCD's L2).
    const int bid = blockIdx.x;
    const int swz = (bid & 7) * 256 + (bid >> 3);
    const int rb = swz >> 4, cb = swz & 15;
    const int m0 = rb * 128, c0 = cb * 32;

    // ---- staging tables: 7 global_load_lds segments per wave ----
    const char* gsrc[7];
    int loff[7];
    {
        int n = 0;
        #pragma unroll
        for (int s0 = 0; s0 < 4; ++s0) {        // A segs: s = w + s0*4 in [0,16)
            const int s = w + s0 * 4;
            const _Float16* pl = (s < 8) ? hiIn : loIn;
            const int seg = (s < 8) ? s : s - 8;
            const int grow = seg * 16 + (l >> 2);
            const int slot = (l & 3) ^ (grow & 3);
            gsrc[n] = (const char*)(pl + (size_t)(m0 + grow) * Hdim) + slot * 16;
            loff[n] = ((s < 8) ? 0 : 8192) + seg * 1024;
            ++n;
        }
        #pragma unroll
        for (int s0 = 0; s0 < 3; ++s0) {        // B segs: s = w + s0*4 in [0,12)
            const int s = w + s0 * 4;
            const _Float16* pl = (s < 6) ? uthi : utlo;
            const int seg = (s < 6) ? s : s - 6;
            const int jrow = seg * 16 + (l >> 2);
            const int g = jrow >> 5, jl = jrow & 31;
            const int slot = (l & 3) ^ (jrow & 3);
            gsrc[n] = (const char*)(pl + (size_t)(g * Hdim + c0 + jl) * Hdim) + slot * 16;
            loff[n] = 16384 + ((s < 6) ? 0 : 6144) + seg * 1024;
            ++n;
        }
    }

    f32x4 acc[2][2][3] = {};   // [mf][nf][gate]

    // prologue stage chunk 0 into buffer 0
    {
        char* lb = smem;
        #pragma unroll
        for (int i = 0; i < 7; ++i)
            __builtin_amdgcn_global_load_lds(
                (const __attribute__((address_space(1))) void*)(gsrc[i]),
                (__attribute__((address_space(3))) void*)(lb + loff[i]), 16, 0, 0);
    }

    const int fr = l & 15;                 // fragment row/col index
    const int kb_lane = l >> 4;            // k-block 0..3
    const int sw_rd = ((kb_lane ^ (l & 3)) << 4);

    for (int kc = 0; kc < 16; ++kc) {
        __syncthreads();                   // drains vm+lgkm: buf[kc&1] ready
        if (kc < 15) {
            char* lb = smem + ((kc + 1) & 1) * 28672;
            const int kbyt = (kc + 1) * 64;
            #pragma unroll
            for (int i = 0; i < 7; ++i)
                __builtin_amdgcn_global_load_lds(
                    (const __attribute__((address_space(1))) void*)(gsrc[i] + kbyt),
                    (__attribute__((address_space(3))) void*)(lb + loff[i]), 16, 0, 0);
        }
        const char* lb = smem + (kc & 1) * 28672;

        half8v ahi[2], alo[2], ahid[2];
        #pragma unroll
        for (int mf = 0; mf < 2; ++mf) {
            const int r = w * 32 + mf * 16 + fr;
            const int byt = r * 64 + sw_rd;
            ahi[mf]  = *(const half8v*)(lb + byt);
            alo[mf]  = *(const half8v*)(lb + 8192 + byt);
            ahid[mf] = ahi[mf] * (_Float16)SPLIT_INV;
        }
        #pragma unroll
        for (int g = 0; g < 3; ++g) {
            #pragma unroll
            for (int nf = 0; nf < 2; ++nf) {
                const int jrow = g * 32 + nf * 16 + fr;
                const int byt = jrow * 64 + sw_rd;
                half8v bhi  = *(const half8v*)(lb + 16384 + byt);
                half8v blo  = *(const half8v*)(lb + 22528 + byt);
                half8v bhid = bhi * (_Float16)SPLIT_INV;
                #pragma unroll
                for (int mf = 0; mf < 2; ++mf) {
                    acc[mf][nf][g] = __builtin_amdgcn_mfma_f32_16x16x32_f16(
                        ahi[mf], bhi, acc[mf][nf][g], 0, 0, 0);
                    acc[mf][nf][g] = __builtin_amdgcn_mfma_f32_16x16x32_f16(
                        ahid[mf], blo, acc[mf][nf][g], 0, 0, 0);
                    acc[mf][nf][g] = __builtin_amdgcn_mfma_f32_16x16x32_f16(
                        alo[mf], bhid, acc[mf][nf][g], 0, 0, 0);
                }
            }
        }
    }

    // ---- GRU cell epilogue ----
    const float* bias1 = gbias + H3;
    float b1z[2], b1r[2], b1h[2];
    #pragma unroll
    for (int nf = 0; nf < 2; ++nf) {
        const int jg = c0 + nf * 16 + fr;
        b1z[nf] = bias1[jg];
        b1r[nf] = bias1[Hdim + jg];
        b1h[nf] = bias1[2 * Hdim + jg];
    }
    #pragma unroll
    for (int mf = 0; mf < 2; ++mf) {
        #pragma unroll
        for (int q = 0; q < 4; ++q) {
            const int r = m0 + w * 32 + mf * 16 + kb_lane * 4 + q;
            const float* xrow = (step == 0) ? gbias : (emb_k + (size_t)sym[r] * H3);
            #pragma unroll
            for (int nf = 0; nf < 2; ++nf) {
                const int jg = c0 + nf * 16 + fr;
                const float xz = xrow[jg];
                const float xr_ = xrow[Hdim + jg];
                const float xh = xrow[2 * Hdim + jg];
                const float az = acc[mf][nf][0][q];
                const float ar = acc[mf][nf][1][q];
                const float ah = acc[mf][nf][2][q];
                const size_t idx = (size_t)r * Hdim + jg;
                const float hold = (float)hiIn[idx] + (float)loIn[idx] * SPLIT_INV;
                const float z  = sigm(xz + b1z[nf] + az);
                const float rr = sigm(xr_ + b1r[nf] + ar);
                const float hh = tanhf(xh + rr * (b1h[nf] + ah));
                const float o = z * hold + (1.0f - z) * hh;
                const _Float16 oh = (_Float16)o;
                hiOut[idx] = oh;
                loOut[idx] = (_Float16)((o - (float)oh) * SPLIT_SC);
                if (hF) hF[idx] = o;
            }
        }
    }
}

// ---------------------------------------------------------------------------
// MFMA output head: logits = h @ Wout^T-split + bout, fused log-softmax /
// entropy / argmax, all register/shuffle resident.
// Block: 64 rows, 4 waves (each 16 rows x 128 cols), BK=32, 16 chunks.
// LDS per buffer (24 KB): Ahi 0..4095, Alo 4096..8191,
//                         Bhi 8192..16383, Blo 16384..24575.
// Same 16B-slot XOR swizzle as k_gru (pre-swizzled global src, swizzled read).
// C/D map: col = l&15, row = (l>>4)*4 + q -> each row's 128 logits live in
// one 16-lane group (8 regs each); softmax = 4-offset shfl_xor reductions.
// ---------------------------------------------------------------------------
__global__ __launch_bounds__(256, 2) void k_out(
    const _Float16* __restrict__ hiP, const _Float16* __restrict__ loP,
    const _Float16* __restrict__ wthi, const _Float16* __restrict__ wtlo, // [128][512]
    const float* __restrict__ bout, int step,
    float* __restrict__ seqO, float* __restrict__ logO,
    float* __restrict__ entO, float* __restrict__ lenO,
    int* __restrict__ symO) {

    __shared__ __align__(16) char smem[2 * 24576];
    const int tid = threadIdx.x;
    const int l = tid & 63, w = tid >> 6;
    const int r0 = blockIdx.x * 64;

    // ---- staging tables: 6 segments per wave (A: 8 segs, B: 16 segs) ----
    const char* gsrc[6];
    int loff[6];
    {
        #pragma unroll
        for (int i = 0; i < 6; ++i) {
            const int s = w + i * 4;
            if (s < 8) {                       // A: h rows r0..r0+63, hi|lo
                const _Float16* pl = (s < 4) ? hiP : loP;
                const int seg = (s < 4) ? s : s - 4;
                const int grow = seg * 16 + (l >> 2);
                const int slot = (l & 3) ^ (grow & 3);
                gsrc[i] = (const char*)(pl + (size_t)(r0 + grow) * Hdim) + slot * 16;
                loff[i] = ((s < 4) ? 0 : 4096) + seg * 1024;
            } else {                           // B: wt rows 0..127, hi|lo
                const int t = s - 8;
                const _Float16* pl = (t < 8) ? wthi : wtlo;
                const int seg = (t < 8) ? t : t - 8;
                const int grow = seg * 16 + (l >> 2);
                const int slot = (l & 3) ^ (grow & 3);
                gsrc[i] = (const char*)(pl + (size_t)grow * Hdim) + slot * 16;
                loff[i] = 8192 + ((t < 8) ? 0 : 8192) + seg * 1024;
            }
        }
    }

    f32x4 acc[8] = {};   // [nf] : cols nf*16 + (l&15)

    {   // prologue: stage chunk 0 into buffer 0
        char* lb = smem;
        #pragma unroll
        for (int i = 0; i < 6; ++i)
            __builtin_amdgcn_global_load_lds(
                (const __attribute__((address_space(1))) void*)(gsrc[i]),
                (__attribute__((address_space(3))) void*)(lb + loff[i]), 16, 0, 0);
    }

    const int fr = l & 15, kb = l >> 4;
    const int sw_rd = ((kb ^ (l & 3)) << 4);

    for (int kc = 0; kc < 16; ++kc) {
        __syncthreads();
        if (kc < 15) {
            char* lb = smem + ((kc + 1) & 1) * 24576;
            const int kbyt = (kc + 1) * 64;
            #pragma unroll
            for (int i = 0; i < 6; ++i)
                __builtin_amdgcn_global_load_lds(
                    (const __attribute__((address_space(1))) void*)(gsrc[i] + kbyt),
                    (__attribute__((address_space(3))) void*)(lb + loff[i]), 16, 0, 0);
        }
        const char* lb = smem + (kc & 1) * 24576;

        const int abyt = (w * 16 + fr) * 64 + sw_rd;
        half8v ahi  = *(const half8v*)(lb + abyt);
        half8v alo  = *(const half8v*)(lb + 4096 + abyt);
        half8v ahid = ahi * (_Float16)SPLIT_INV;
        #pragma unroll
        for (int nf = 0; nf < 8; ++nf) {
            const int bbyt = (nf * 16 + fr) * 64 + sw_rd;
            half8v bhi  = *(const half8v*)(lb + 8192 + bbyt);
            half8v blo  = *(const half8v*)(lb + 16384 + bbyt);
            half8v bhid = bhi * (_Float16)SPLIT_INV;
            acc[nf] = __builtin_amdgcn_mfma_f32_16x16x32_f16(ahi,  bhi,  acc[nf], 0, 0, 0);
            acc[nf] = __builtin_amdgcn_mfma_f32_16x16x32_f16(ahid, blo,  acc[nf], 0, 0, 0);
            acc[nf] = __builtin_amdgcn_mfma_f32_16x16x32_f16(alo,  bhid, acc[nf], 0, 0, 0);
        }
    }

    // ---- fused log-softmax / entropy / argmax epilogue ----
    float bo[8];
    #pragma unroll
    for (int nf = 0; nf < 8; ++nf) bo[nf] = bout[nf * 16 + fr];

    #pragma unroll
    for (int q = 0; q < 4; ++q) {
        float vals[8];
        #pragma unroll
        for (int nf = 0; nf < 8; ++nf) vals[nf] = acc[nf][q] + bo[nf];

        float vmax = vals[0]; int vidx = fr;
        #pragma unroll
        for (int nf = 1; nf < 8; ++nf)
            if (vals[nf] > vmax) { vmax = vals[nf]; vidx = nf * 16 + fr; }
        #pragma unroll
        for (int off = 1; off < 16; off <<= 1) {
            const float ov = __shfl_xor(vmax, off);
            const int   oi = __shfl_xor(vidx, off);
            if (ov > vmax || (ov == vmax && oi < vidx)) { vmax = ov; vidx = oi; }
        }

        float s = 0.0f, t2 = 0.0f;
        #pragma unroll
        for (int nf = 0; nf < 8; ++nf) {
            const float d = vals[nf] - vmax;
            const float e = __expf(d);
            s += e; t2 = fmaf(e, d, t2);
        }
        #pragma unroll
        for (int off = 1; off < 16; off <<= 1) {
            s  += __shfl_xor(s, off);
            t2 += __shfl_xor(t2, off);
        }

        if (fr == 0) {                       // one writer lane per 16-lane group
            const int rg = r0 + w * 16 + kb * 4 + q;
            const float logS = logf(s);
            const float ent  = logS - t2 / s;
            seqO[rg * Lmsg + step] = (float)vidx;
            logO[rg * Lmsg + step] = -logS;
            symO[rg] = vidx;
            if (step == 0) { entO[rg] = ent * (1.0f / Lmsg); lenO[rg] = (float)Lmsg; }
            else           { entO[rg] += ent * (1.0f / Lmsg); }
        }
    }
}

} // namespace

extern "C" void kernel_launch(void* const* d_in, const int* in_sizes, int n_in,
                              void* d_out, int out_size, void* d_ws, size_t ws_size,
                              hipStream_t stream) {
    (void)in_sizes; (void)n_in; (void)out_size; (void)ws_size;

    const float* inputs = (const float*)d_in[0];
    const float* W_vh   = (const float*)d_in[1];
    const float* b_vh   = (const float*)d_in[2];
    const float* gk     = (const float*)d_in[3];
    const float* guk    = (const float*)d_in[4];
    const float* gbias  = (const float*)d_in[5];   // [2][3H]
    const float* Wout   = (const float*)d_in[6];
    const float* bout   = (const float*)d_in[7];
    const float* emb    = (const float*)d_in[8];

    float* out  = (float*)d_out;
    float* seqO = out;
    float* logO = out + (size_t)Bsz * Lmsg;
    float* entO = out + (size_t)2 * Bsz * Lmsg;
    float* lenO = entO + Bsz;
    float* hF   = lenO + Bsz;                       // [B,H] f32 final h_t

    char* wsb = (char*)d_ws;
    const size_t PLANE = (size_t)Bsz * Hdim * sizeof(_Float16);  // 16 MiB
    _Float16* pH[2] = { (_Float16*)(wsb),             (_Float16*)(wsb + 2 * PLANE) };
    _Float16* pL[2] = { (_Float16*)(wsb + PLANE),     (_Float16*)(wsb + 3 * PLANE) };
    _Float16* uthi  = (_Float16*)(wsb + 4 * PLANE);
    _Float16* utlo  = uthi + (size_t)H3 * Hdim;
    _Float16* wthi  = utlo + (size_t)H3 * Hdim;
    _Float16* wtlo  = wthi + (size_t)Vdim * Hdim;
    float*    emb_k = (float*)(wtlo + (size_t)Vdim * Hdim);
    int*      sym   = (int*)(emb_k + (size_t)Vdim * H3);

    k_embk  <<<dim3(Vdim * H3 / 256), 256, 0, stream>>>(emb, gk, gbias, emb_k, sym);
    k_usplit<<<dim3(H3 * Hdim / 256), 256, 0, stream>>>(guk, uthi, utlo);
    k_osplit<<<dim3(Vdim * Hdim / 256), 256, 0, stream>>>(Wout, wthi, wtlo);
    k_vision<<<dim3(Hdim / 64, Bsz / 128), 256, 0, stream>>>(inputs, W_vh, b_vh, pH[0], pL[0]);

    for (int t = 0; t < Lmsg; ++t) {
        const int rd = t & 1, wr = (t + 1) & 1;
        k_gru<<<dim3((Bsz / 128) * (Hdim / 32)), 256, 0, stream>>>(
            pH[rd], pL[rd], uthi, utlo, gbias, emb_k, sym, t,
            pH[wr], pL[wr], (t == Lmsg - 1) ? hF : nullptr);
        k_out<<<dim3(Bsz / 64), 256, 0, stream>>>(
            pH[wr], pL[wr], wthi, wtlo, bout, t, seqO, logO, entO, lenO, sym);
    }
}

// Round 9
// 1387.463 us; speedup vs baseline: 2.9888x; 1.0792x over previous
//
#include <hip/hip_runtime.h>
#include <math.h>

namespace {

constexpr int Bsz  = 16384;
constexpr int Fdim = 512;
constexpr int Hdim = 512;
constexpr int Vdim = 128;
constexpr int Lmsg = 10;
constexpr int H3   = 3 * Hdim;   // 1536

// f16 split scale: x = hi + lo/32 ; scales cancel per product, so all three
// MFMAs (hi*hi, hi/32*lo32, lo32*hi/32) share one fp32 accumulator.
constexpr float SPLIT_SC  = 32.0f;
constexpr float SPLIT_INV = 0.03125f;

typedef _Float16 half4v __attribute__((ext_vector_type(4)));
typedef _Float16 half8v __attribute__((ext_vector_type(8)));
typedef float    f32x4  __attribute__((ext_vector_type(4)));

__device__ __forceinline__ float sigm(float x) { return 1.0f / (1.0f + __expf(-x)); }

// ---------------------------------------------------------------------------
// emb_k[v][j] = sum_e embedding[v][e] * gru_kernel[e][j] + bias0[j]  (fp32)
// ---------------------------------------------------------------------------
__global__ void k_embk(const float* __restrict__ emb, const float* __restrict__ gk,
                       const float* __restrict__ bias0, float* __restrict__ emb_k,
                       int* __restrict__ sym) {
    const int gid = blockIdx.x * 256 + threadIdx.x;       // V*H3 = 196608 threads
    const int v = gid / H3, j = gid - v * H3;
    float acc = bias0[j];
    const float* er = emb + v * 128;
    #pragma unroll 4
    for (int e = 0; e < 128; ++e) acc = fmaf(er[e], gk[e * H3 + j], acc);
    emb_k[gid] = acc;
    if (gid < Bsz) sym[gid] = 0;
}

// ---------------------------------------------------------------------------
// Generic split+transpose: src fp32 [512][N] -> dhi/dlo f16 [N][512]
// (used for gru_rec_kernel N=1536, W_out N=128, W_vh N=512; one-shot)
// ---------------------------------------------------------------------------
__global__ void k_split(const float* __restrict__ src,
                        _Float16* __restrict__ dhi, _Float16* __restrict__ dlo,
                        int N) {
    const int gid = blockIdx.x * 256 + threadIdx.x;  // over N*512
    const int j = gid >> 9, k = gid & 511;
    const float u = src[(size_t)k * N + j];
    const _Float16 hi = (_Float16)u;
    dhi[gid] = hi;                                    // [j][k]
    dlo[gid] = (_Float16)((u - (float)hi) * SPLIT_SC);
}

// ---------------------------------------------------------------------------
// Elementwise split (no transpose): inputs fp32 [B][512] -> hi/lo planes
// ---------------------------------------------------------------------------
__global__ void k_asplit(const float* __restrict__ x,
                         _Float16* __restrict__ hi, _Float16* __restrict__ lo) {
    const size_t i = ((size_t)blockIdx.x * 256 + threadIdx.x) * 4;
    const float4 v = *(const float4*)(x + i);
    half4v h, l;
    h.x = (_Float16)v.x; l.x = (_Float16)((v.x - (float)h.x) * SPLIT_SC);
    h.y = (_Float16)v.y; l.y = (_Float16)((v.y - (float)h.y) * SPLIT_SC);
    h.z = (_Float16)v.z; l.z = (_Float16)((v.z - (float)h.z) * SPLIT_SC);
    h.w = (_Float16)v.w; l.w = (_Float16)((v.w - (float)h.w) * SPLIT_SC);
    *(half4v*)(hi + i) = h;
    *(half4v*)(lo + i) = l;
}

// ---------------------------------------------------------------------------
// MFMA vision head: h0 = tanh(inputs @ W_vh + b_vh) -> f16 hi/lo planes.
// Clone of k_out's GEMM body (64 rows x 128 cols per block, BK=32, 4 waves,
// 24 KB/buffer double-buffered, same XOR-slot swizzle); epilogue = tanh+split.
// Grid: 256 row-blocks x 4 col-blocks = 1024, XCD-swizzled (1024%8==0).
// ---------------------------------------------------------------------------
__global__ __launch_bounds__(256, 2) void k_vision2(
    const _Float16* __restrict__ aHi, const _Float16* __restrict__ aLo,  // [B][512]
    const _Float16* __restrict__ wvhi, const _Float16* __restrict__ wvlo, // [512][512]
    const float* __restrict__ bias,
    _Float16* __restrict__ hiP, _Float16* __restrict__ loP) {

    __shared__ __align__(16) char smem[2 * 24576];
    const int tid = threadIdx.x;
    const int l = tid & 63, w = tid >> 6;

    const int bid = blockIdx.x;
    const int swz = (bid & 7) * 128 + (bid >> 3);
    const int rb = swz >> 2, cb = swz & 3;
    const int r0 = rb * 64, c0 = cb * 128;

    // ---- staging tables: 6 segments per wave (A: 8 segs, B: 16 segs) ----
    const char* gsrc[6];
    int loff[6];
    {
        #pragma unroll
        for (int i = 0; i < 6; ++i) {
            const int s = w + i * 4;
            if (s < 8) {                       // A: rows r0..r0+63, hi|lo
                const _Float16* pl = (s < 4) ? aHi : aLo;
                const int seg = s & 3;
                const int grow = seg * 16 + (l >> 2);
                const int slot = (l & 3) ^ (grow & 3);
                gsrc[i] = (const char*)(pl + (size_t)(r0 + grow) * Hdim) + slot * 16;
                loff[i] = ((s < 4) ? 0 : 4096) + seg * 1024;
            } else {                           // B: wv rows c0..c0+127, hi|lo
                const int t = s - 8;
                const _Float16* pl = (t < 8) ? wvhi : wvlo;
                const int seg = t & 7;
                const int grow = seg * 16 + (l >> 2);
                const int slot = (l & 3) ^ (grow & 3);
                gsrc[i] = (const char*)(pl + (size_t)(c0 + grow) * Hdim) + slot * 16;
                loff[i] = 8192 + ((t < 8) ? 0 : 8192) + seg * 1024;
            }
        }
    }

    f32x4 acc[8] = {};   // [nf] : cols c0 + nf*16 + (l&15)

    {   // prologue: stage chunk 0 into buffer 0
        char* lb = smem;
        #pragma unroll
        for (int i = 0; i < 6; ++i)
            __builtin_amdgcn_global_load_lds(
                (const __attribute__((address_space(1))) void*)(gsrc[i]),
                (__attribute__((address_space(3))) void*)(lb + loff[i]), 16, 0, 0);
    }

    const int fr = l & 15, kb = l >> 4;
    const int sw_rd = ((kb ^ (l & 3)) << 4);

    for (int kc = 0; kc < 16; ++kc) {
        __syncthreads();
        if (kc < 15) {
            char* lb = smem + ((kc + 1) & 1) * 24576;
            const int kbyt = (kc + 1) * 64;
            #pragma unroll
            for (int i = 0; i < 6; ++i)
                __builtin_amdgcn_global_load_lds(
                    (const __attribute__((address_space(1))) void*)(gsrc[i] + kbyt),
                    (__attribute__((address_space(3))) void*)(lb + loff[i]), 16, 0, 0);
        }
        const char* lb = smem + (kc & 1) * 24576;

        const int abyt = (w * 16 + fr) * 64 + sw_rd;
        half8v ahi  = *(const half8v*)(lb + abyt);
        half8v alo  = *(const half8v*)(lb + 4096 + abyt);
        half8v ahid = ahi * (_Float16)SPLIT_INV;
        #pragma unroll
        for (int nf = 0; nf < 8; ++nf) {
            const int bbyt = (nf * 16 + fr) * 64 + sw_rd;
            half8v bhi  = *(const half8v*)(lb + 8192 + bbyt);
            half8v blo  = *(const half8v*)(lb + 16384 + bbyt);
            half8v bhid = bhi * (_Float16)SPLIT_INV;
            acc[nf] = __builtin_amdgcn_mfma_f32_16x16x32_f16(ahi,  bhi,  acc[nf], 0, 0, 0);
            acc[nf] = __builtin_amdgcn_mfma_f32_16x16x32_f16(ahid, blo,  acc[nf], 0, 0, 0);
            acc[nf] = __builtin_amdgcn_mfma_f32_16x16x32_f16(alo,  bhid, acc[nf], 0, 0, 0);
        }
    }

    // ---- tanh + split-store epilogue ----
    float bo[8];
    #pragma unroll
    for (int nf = 0; nf < 8; ++nf) bo[nf] = bias[c0 + nf * 16 + fr];

    #pragma unroll
    for (int q = 0; q < 4; ++q) {
        const int r = r0 + w * 16 + kb * 4 + q;
        #pragma unroll
        for (int nf = 0; nf < 8; ++nf) {
            const float o = tanhf(acc[nf][q] + bo[nf]);
            const _Float16 oh = (_Float16)o;
            const size_t idx = (size_t)r * Hdim + c0 + nf * 16 + fr;
            hiP[idx] = oh;
            loP[idx] = (_Float16)((o - (float)oh) * SPLIT_SC);
        }
    }
}

// ---------------------------------------------------------------------------
// MFMA GRU step. Tile: 128 rows x 32 cols x 3 gates, BK=32, 4 waves.
// LDS double-buffered, 28 KB/buffer: Ahi|Alo|Bhi|Blo. 16B-slot XOR swizzle
// (pre-swizzled global src since global_load_lds writes linearly; read
// applies the same involution).
// ---------------------------------------------------------------------------
__global__ __launch_bounds__(256, 2) void k_gru(
    const _Float16* __restrict__ hiIn, const _Float16* __restrict__ loIn,
    const _Float16* __restrict__ uthi, const _Float16* __restrict__ utlo,
    const float* __restrict__ gbias,   // [2][1536]
    const float* __restrict__ emb_k,   // [128][1536] (includes bias0)
    const int* __restrict__ sym,
    int step,
    _Float16* __restrict__ hiOut, _Float16* __restrict__ loOut,
    float* __restrict__ hF) {          // non-null on last step: f32 h_t out

    __shared__ __align__(16) char smem[2 * 28672];
    const int tid = threadIdx.x;
    const int l = tid & 63, w = tid >> 6;

    const int bid = blockIdx.x;
    const int swz = (bid & 7) * 256 + (bid >> 3);
    const int rb = swz >> 4, cb = swz & 15;
    const int m0 = rb * 128, c0 = cb * 32;

    // ---- staging tables: 7 global_load_lds segments per wave ----
    const char* gsrc[7];
    int loff[7];
    {
        int n = 0;
        #pragma unroll
        for (int s0 = 0; s0 < 4; ++s0) {        // A segs: s = w + s0*4 in [0,16)
            const int s = w + s0 * 4;
            const _Float16* pl = (s < 8) ? hiIn : loIn;
            const int seg = (s < 8) ? s : s - 8;
            const int grow = seg * 16 + (l >> 2);
            const int slot = (l & 3) ^ (grow & 3);
            gsrc[n] = (const char*)(pl + (size_t)(m0 + grow) * Hdim) + slot * 16;
            loff[n] = ((s < 8) ? 0 : 8192) + seg * 1024;
            ++n;
        }
        #pragma unroll
        for (int s0 = 0; s0 < 3; ++s0) {        // B segs: s = w + s0*4 in [0,12)
            const int s = w + s0 * 4;
            const _Float16* pl = (s < 6) ? uthi : utlo;
            const int seg = (s < 6) ? s : s - 6;
            const int jrow = seg * 16 + (l >> 2);
            const int g = jrow >> 5, jl = jrow & 31;
            const int slot = (l & 3) ^ (jrow & 3);
            gsrc[n] = (const char*)(pl + (size_t)(g * Hdim + c0 + jl) * Hdim) + slot * 16;
            loff[n] = 16384 + ((s < 6) ? 0 : 6144) + seg * 1024;
            ++n;
        }
    }

    f32x4 acc[2][2][3] = {};   // [mf][nf][gate]

    // prologue stage chunk 0 into buffer 0
    {
        char* lb = smem;
        #pragma unroll
        for (int i = 0; i < 7; ++i)
            __builtin_amdgcn_global_load_lds(
                (const __attribute__((address_space(1))) void*)(gsrc[i]),
                (__attribute__((address_space(3))) void*)(lb + loff[i]), 16, 0, 0);
    }

    const int fr = l & 15;                 // fragment row/col index
    const int kb_lane = l >> 4;            // k-block 0..3
    const int sw_rd = ((kb_lane ^ (l & 3)) << 4);

    for (int kc = 0; kc < 16; ++kc) {
        __syncthreads();                   // drains vm+lgkm: buf[kc&1] ready
        if (kc < 15) {
            char* lb = smem + ((kc + 1) & 1) * 28672;
            const int kbyt = (kc + 1) * 64;
            #pragma unroll
            for (int i = 0; i < 7; ++i)
                __builtin_amdgcn_global_load_lds(
                    (const __attribute__((address_space(1))) void*)(gsrc[i] + kbyt),
                    (__attribute__((address_space(3))) void*)(lb + loff[i]), 16, 0, 0);
        }
        const char* lb = smem + (kc & 1) * 28672;

        half8v ahi[2], alo[2], ahid[2];
        #pragma unroll
        for (int mf = 0; mf < 2; ++mf) {
            const int r = w * 32 + mf * 16 + fr;
            const int byt = r * 64 + sw_rd;
            ahi[mf]  = *(const half8v*)(lb + byt);
            alo[mf]  = *(const half8v*)(lb + 8192 + byt);
            ahid[mf] = ahi[mf] * (_Float16)SPLIT_INV;
        }
        #pragma unroll
        for (int g = 0; g < 3; ++g) {
            #pragma unroll
            for (int nf = 0; nf < 2; ++nf) {
                const int jrow = g * 32 + nf * 16 + fr;
                const int byt = jrow * 64 + sw_rd;
                half8v bhi  = *(const half8v*)(lb + 16384 + byt);
                half8v blo  = *(const half8v*)(lb + 22528 + byt);
                half8v bhid = bhi * (_Float16)SPLIT_INV;
                #pragma unroll
                for (int mf = 0; mf < 2; ++mf) {
                    acc[mf][nf][g] = __builtin_amdgcn_mfma_f32_16x16x32_f16(
                        ahi[mf], bhi, acc[mf][nf][g], 0, 0, 0);
                    acc[mf][nf][g] = __builtin_amdgcn_mfma_f32_16x16x32_f16(
                        ahid[mf], blo, acc[mf][nf][g], 0, 0, 0);
                    acc[mf][nf][g] = __builtin_amdgcn_mfma_f32_16x16x32_f16(
                        alo[mf], bhid, acc[mf][nf][g], 0, 0, 0);
                }
            }
        }
    }

    // ---- GRU cell epilogue ----
    const float* bias1 = gbias + H3;
    float b1z[2], b1r[2], b1h[2];
    #pragma unroll
    for (int nf = 0; nf < 2; ++nf) {
        const int jg = c0 + nf * 16 + fr;
        b1z[nf] = bias1[jg];
        b1r[nf] = bias1[Hdim + jg];
        b1h[nf] = bias1[2 * Hdim + jg];
    }
    #pragma unroll
    for (int mf = 0; mf < 2; ++mf) {
        #pragma unroll
        for (int q = 0; q < 4; ++q) {
            const int r = m0 + w * 32 + mf * 16 + kb_lane * 4 + q;
            const float* xrow = (step == 0) ? gbias : (emb_k + (size_t)sym[r] * H3);
            #pragma unroll
            for (int nf = 0; nf < 2; ++nf) {
                const int jg = c0 + nf * 16 + fr;
                const float xz = xrow[jg];
                const float xr_ = xrow[Hdim + jg];
                const float xh = xrow[2 * Hdim + jg];
                const float az = acc[mf][nf][0][q];
                const float ar = acc[mf][nf][1][q];
                const float ah = acc[mf][nf][2][q];
                const size_t idx = (size_t)r * Hdim + jg;
                const float hold = (float)hiIn[idx] + (float)loIn[idx] * SPLIT_INV;
                const float z  = sigm(xz + b1z[nf] + az);
                const float rr = sigm(xr_ + b1r[nf] + ar);
                const float hh = tanhf(xh + rr * (b1h[nf] + ah));
                const float o = z * hold + (1.0f - z) * hh;
                const _Float16 oh = (_Float16)o;
                hiOut[idx] = oh;
                loOut[idx] = (_Float16)((o - (float)oh) * SPLIT_SC);
                if (hF) hF[idx] = o;
            }
        }
    }
}

// ---------------------------------------------------------------------------
// MFMA output head: logits = h @ Wout^T-split + bout, fused log-softmax /
// entropy / argmax, all register/shuffle resident. (validated round 6)
// ---------------------------------------------------------------------------
__global__ __launch_bounds__(256, 2) void k_out(
    const _Float16* __restrict__ hiP, const _Float16* __restrict__ loP,
    const _Float16* __restrict__ wthi, const _Float16* __restrict__ wtlo, // [128][512]
    const float* __restrict__ bout, int step,
    float* __restrict__ seqO, float* __restrict__ logO,
    float* __restrict__ entO, float* __restrict__ lenO,
    int* __restrict__ symO) {

    __shared__ __align__(16) char smem[2 * 24576];
    const int tid = threadIdx.x;
    const int l = tid & 63, w = tid >> 6;
    const int r0 = blockIdx.x * 64;

    const char* gsrc[6];
    int loff[6];
    {
        #pragma unroll
        for (int i = 0; i < 6; ++i) {
            const int s = w + i * 4;
            if (s < 8) {                       // A: h rows r0..r0+63, hi|lo
                const _Float16* pl = (s < 4) ? hiP : loP;
                const int seg = (s < 4) ? s : s - 4;
                const int grow = seg * 16 + (l >> 2);
                const int slot = (l & 3) ^ (grow & 3);
                gsrc[i] = (const char*)(pl + (size_t)(r0 + grow) * Hdim) + slot * 16;
                loff[i] = ((s < 4) ? 0 : 4096) + seg * 1024;
            } else {                           // B: wt rows 0..127, hi|lo
                const int t = s - 8;
                const _Float16* pl = (t < 8) ? wthi : wtlo;
                const int seg = (t < 8) ? t : t - 8;
                const int grow = seg * 16 + (l >> 2);
                const int slot = (l & 3) ^ (grow & 3);
                gsrc[i] = (const char*)(pl + (size_t)grow * Hdim) + slot * 16;
                loff[i] = 8192 + ((t < 8) ? 0 : 8192) + seg * 1024;
            }
        }
    }

    f32x4 acc[8] = {};   // [nf] : cols nf*16 + (l&15)

    {   // prologue: stage chunk 0 into buffer 0
        char* lb = smem;
        #pragma unroll
        for (int i = 0; i < 6; ++i)
            __builtin_amdgcn_global_load_lds(
                (const __attribute__((address_space(1))) void*)(gsrc[i]),
                (__attribute__((address_space(3))) void*)(lb + loff[i]), 16, 0, 0);
    }

    const int fr = l & 15, kb = l >> 4;
    const int sw_rd = ((kb ^ (l & 3)) << 4);

    for (int kc = 0; kc < 16; ++kc) {
        __syncthreads();
        if (kc < 15) {
            char* lb = smem + ((kc + 1) & 1) * 24576;
            const int kbyt = (kc + 1) * 64;
            #pragma unroll
            for (int i = 0; i < 6; ++i)
                __builtin_amdgcn_global_load_lds(
                    (const __attribute__((address_space(1))) void*)(gsrc[i] + kbyt),
                    (__attribute__((address_space(3))) void*)(lb + loff[i]), 16, 0, 0);
        }
        const char* lb = smem + (kc & 1) * 24576;

        const int abyt = (w * 16 + fr) * 64 + sw_rd;
        half8v ahi  = *(const half8v*)(lb + abyt);
        half8v alo  = *(const half8v*)(lb + 4096 + abyt);
        half8v ahid = ahi * (_Float16)SPLIT_INV;
        #pragma unroll
        for (int nf = 0; nf < 8; ++nf) {
            const int bbyt = (nf * 16 + fr) * 64 + sw_rd;
            half8v bhi  = *(const half8v*)(lb + 8192 + bbyt);
            half8v blo  = *(const half8v*)(lb + 16384 + bbyt);
            half8v bhid = bhi * (_Float16)SPLIT_INV;
            acc[nf] = __builtin_amdgcn_mfma_f32_16x16x32_f16(ahi,  bhi,  acc[nf], 0, 0, 0);
            acc[nf] = __builtin_amdgcn_mfma_f32_16x16x32_f16(ahid, blo,  acc[nf], 0, 0, 0);
            acc[nf] = __builtin_amdgcn_mfma_f32_16x16x32_f16(alo,  bhid, acc[nf], 0, 0, 0);
        }
    }

    // ---- fused log-softmax / entropy / argmax epilogue ----
    float bo[8];
    #pragma unroll
    for (int nf = 0; nf < 8; ++nf) bo[nf] = bout[nf * 16 + fr];

    #pragma unroll
    for (int q = 0; q < 4; ++q) {
        float vals[8];
        #pragma unroll
        for (int nf = 0; nf < 8; ++nf) vals[nf] = acc[nf][q] + bo[nf];

        float vmax = vals[0]; int vidx = fr;
        #pragma unroll
        for (int nf = 1; nf < 8; ++nf)
            if (vals[nf] > vmax) { vmax = vals[nf]; vidx = nf * 16 + fr; }
        #pragma unroll
        for (int off = 1; off < 16; off <<= 1) {
            const float ov = __shfl_xor(vmax, off);
            const int   oi = __shfl_xor(vidx, off);
            if (ov > vmax || (ov == vmax && oi < vidx)) { vmax = ov; vidx = oi; }
        }

        float s = 0.0f, t2 = 0.0f;
        #pragma unroll
        for (int nf = 0; nf < 8; ++nf) {
            const float d = vals[nf] - vmax;
            const float e = __expf(d);
            s += e; t2 = fmaf(e, d, t2);
        }
        #pragma unroll
        for (int off = 1; off < 16; off <<= 1) {
            s  += __shfl_xor(s, off);
            t2 += __shfl_xor(t2, off);
        }

        if (fr == 0) {
            const int rg = r0 + w * 16 + kb * 4 + q;
            const float logS = logf(s);
            const float ent  = logS - t2 / s;
            seqO[rg * Lmsg + step] = (float)vidx;
            logO[rg * Lmsg + step] = -logS;
            symO[rg] = vidx;
            if (step == 0) { entO[rg] = ent * (1.0f / Lmsg); lenO[rg] = (float)Lmsg; }
            else           { entO[rg] += ent * (1.0f / Lmsg); }
        }
    }
}

} // namespace

extern "C" void kernel_launch(void* const* d_in, const int* in_sizes, int n_in,
                              void* d_out, int out_size, void* d_ws, size_t ws_size,
                              hipStream_t stream) {
    (void)in_sizes; (void)n_in; (void)out_size; (void)ws_size;

    const float* inputs = (const float*)d_in[0];
    const float* W_vh   = (const float*)d_in[1];
    const float* b_vh   = (const float*)d_in[2];
    const float* gk     = (const float*)d_in[3];
    const float* guk    = (const float*)d_in[4];
    const float* gbias  = (const float*)d_in[5];   // [2][3H]
    const float* Wout   = (const float*)d_in[6];
    const float* bout   = (const float*)d_in[7];
    const float* emb    = (const float*)d_in[8];

    float* out  = (float*)d_out;
    float* seqO = out;
    float* logO = out + (size_t)Bsz * Lmsg;
    float* entO = out + (size_t)2 * Bsz * Lmsg;
    float* lenO = entO + Bsz;
    float* hF   = lenO + Bsz;                       // [B,H] f32 final h_t

    char* wsb = (char*)d_ws;
    const size_t PLANE = (size_t)Bsz * Hdim * sizeof(_Float16);  // 16 MiB
    _Float16* pH[2] = { (_Float16*)(wsb),             (_Float16*)(wsb + 2 * PLANE) };
    _Float16* pL[2] = { (_Float16*)(wsb + PLANE),     (_Float16*)(wsb + 3 * PLANE) };
    // inputs hi/lo planes live in pH[1]/pL[1]'s space (dead until gru step 0)
    _Float16* aHi   = pH[1];
    _Float16* aLo   = pL[1];
    _Float16* uthi  = (_Float16*)(wsb + 4 * PLANE);
    _Float16* utlo  = uthi + (size_t)H3 * Hdim;
    _Float16* wthi  = utlo + (size_t)H3 * Hdim;
    _Float16* wtlo  = wthi + (size_t)Vdim * Hdim;
    _Float16* wvhi  = wtlo + (size_t)Vdim * Hdim;
    _Float16* wvlo  = wvhi + (size_t)Hdim * Hdim;
    float*    emb_k = (float*)(wvlo + (size_t)Hdim * Hdim);
    int*      sym   = (int*)(emb_k + (size_t)Vdim * H3);

    k_embk  <<<dim3(Vdim * H3 / 256), 256, 0, stream>>>(emb, gk, gbias, emb_k, sym);
    k_split <<<dim3(H3 * Hdim / 256), 256, 0, stream>>>(guk, uthi, utlo, H3);
    k_split <<<dim3(Vdim * Hdim / 256), 256, 0, stream>>>(Wout, wthi, wtlo, Vdim);
    k_split <<<dim3(Hdim * Hdim / 256), 256, 0, stream>>>(W_vh, wvhi, wvlo, Hdim);
    k_asplit<<<dim3(Bsz * Fdim / 1024), 256, 0, stream>>>(inputs, aHi, aLo);
    k_vision2<<<dim3((Bsz / 64) * 4), 256, 0, stream>>>(aHi, aLo, wvhi, wvlo, b_vh,
                                                        pH[0], pL[0]);

    for (int t = 0; t < Lmsg; ++t) {
        const int rd = t & 1, wr = (t + 1) & 1;
        k_gru<<<dim3((Bsz / 128) * (Hdim / 32)), 256, 0, stream>>>(
            pH[rd], pL[rd], uthi, utlo, gbias, emb_k, sym, t,
            pH[wr], pL[wr], (t == Lmsg - 1) ? hF : nullptr);
        k_out<<<dim3(Bsz / 64), 256, 0, stream>>>(
            pH[wr], pL[wr], wthi, wtlo, bout, t, seqO, logO, entO, lenO, sym);
    }
}

// Round 11
// 1331.916 us; speedup vs baseline: 3.1135x; 1.0417x over previous
//
#include <hip/hip_runtime.h>
#include <math.h>

namespace {

constexpr int Bsz  = 16384;
constexpr int Fdim = 512;
constexpr int Hdim = 512;
constexpr int Vdim = 128;
constexpr int Lmsg = 10;
constexpr int H3   = 3 * Hdim;   // 1536

// f16 split scale: x = hi + lo/32 ; scales cancel per product, so all three
// MFMAs (hi*hi, hi/32*lo32, lo32*hi/32) share one fp32 accumulator.
constexpr float SPLIT_SC  = 32.0f;
constexpr float SPLIT_INV = 0.03125f;

typedef _Float16 half4v __attribute__((ext_vector_type(4)));
typedef _Float16 half8v __attribute__((ext_vector_type(8)));
typedef float    f32x4  __attribute__((ext_vector_type(4)));

__device__ __forceinline__ float sigm(float x) { return 1.0f / (1.0f + __expf(-x)); }

// ---------------------------------------------------------------------------
// emb_k[v][j] = sum_e embedding[v][e] * gru_kernel[e][j] + bias0[j]  (fp32)
// ---------------------------------------------------------------------------
__global__ void k_embk(const float* __restrict__ emb, const float* __restrict__ gk,
                       const float* __restrict__ bias0, float* __restrict__ emb_k,
                       int* __restrict__ sym) {
    const int gid = blockIdx.x * 256 + threadIdx.x;       // V*H3 = 196608 threads
    const int v = gid / H3, j = gid - v * H3;
    float acc = bias0[j];
    const float* er = emb + v * 128;
    #pragma unroll 4
    for (int e = 0; e < 128; ++e) acc = fmaf(er[e], gk[e * H3 + j], acc);
    emb_k[gid] = acc;
    if (gid < Bsz) sym[gid] = 0;
}

// ---------------------------------------------------------------------------
// Generic split+transpose: src fp32 [512][N] -> dhi/dlo f16 [N][512]
// ---------------------------------------------------------------------------
__global__ void k_split(const float* __restrict__ src,
                        _Float16* __restrict__ dhi, _Float16* __restrict__ dlo,
                        int N) {
    const int gid = blockIdx.x * 256 + threadIdx.x;  // over N*512
    const int j = gid >> 9, k = gid & 511;
    const float u = src[(size_t)k * N + j];
    const _Float16 hi = (_Float16)u;
    dhi[gid] = hi;                                    // [j][k]
    dlo[gid] = (_Float16)((u - (float)hi) * SPLIT_SC);
}

// ---------------------------------------------------------------------------
// Elementwise split (no transpose): inputs fp32 [B][512] -> hi/lo planes
// ---------------------------------------------------------------------------
__global__ void k_asplit(const float* __restrict__ x,
                         _Float16* __restrict__ hi, _Float16* __restrict__ lo) {
    const size_t i = ((size_t)blockIdx.x * 256 + threadIdx.x) * 4;
    const float4 v = *(const float4*)(x + i);
    half4v h, l;
    h.x = (_Float16)v.x; l.x = (_Float16)((v.x - (float)h.x) * SPLIT_SC);
    h.y = (_Float16)v.y; l.y = (_Float16)((v.y - (float)h.y) * SPLIT_SC);
    h.z = (_Float16)v.z; l.z = (_Float16)((v.z - (float)h.z) * SPLIT_SC);
    h.w = (_Float16)v.w; l.w = (_Float16)((v.w - (float)h.w) * SPLIT_SC);
    *(half4v*)(hi + i) = h;
    *(half4v*)(lo + i) = l;
}

// ---------------------------------------------------------------------------
// MFMA vision head: h0 = tanh(inputs @ W_vh + b_vh) -> f16 hi/lo planes.
// (validated round 9: part of the −110 µs vision win)
// ---------------------------------------------------------------------------
__global__ __launch_bounds__(256, 2) void k_vision2(
    const _Float16* __restrict__ aHi, const _Float16* __restrict__ aLo,  // [B][512]
    const _Float16* __restrict__ wvhi, const _Float16* __restrict__ wvlo, // [512][512]
    const float* __restrict__ bias,
    _Float16* __restrict__ hiP, _Float16* __restrict__ loP) {

    __shared__ __align__(16) char smem[2 * 24576];
    const int tid = threadIdx.x;
    const int l = tid & 63, w = tid >> 6;

    const int bid = blockIdx.x;
    const int swz = (bid & 7) * 128 + (bid >> 3);
    const int rb = swz >> 2, cb = swz & 3;
    const int r0 = rb * 64, c0 = cb * 128;

    const char* gsrc[6];
    int loff[6];
    {
        #pragma unroll
        for (int i = 0; i < 6; ++i) {
            const int s = w + i * 4;
            if (s < 8) {                       // A: rows r0..r0+63, hi|lo
                const _Float16* pl = (s < 4) ? aHi : aLo;
                const int seg = s & 3;
                const int grow = seg * 16 + (l >> 2);
                const int slot = (l & 3) ^ (grow & 3);
                gsrc[i] = (const char*)(pl + (size_t)(r0 + grow) * Hdim) + slot * 16;
                loff[i] = ((s < 4) ? 0 : 4096) + seg * 1024;
            } else {                           // B: wv rows c0..c0+127, hi|lo
                const int t = s - 8;
                const _Float16* pl = (t < 8) ? wvhi : wvlo;
                const int seg = t & 7;
                const int grow = seg * 16 + (l >> 2);
                const int slot = (l & 3) ^ (grow & 3);
                gsrc[i] = (const char*)(pl + (size_t)(c0 + grow) * Hdim) + slot * 16;
                loff[i] = 8192 + ((t < 8) ? 0 : 8192) + seg * 1024;
            }
        }
    }

    f32x4 acc[8] = {};   // [nf] : cols c0 + nf*16 + (l&15)

    {   // prologue: stage chunk 0 into buffer 0
        char* lb = smem;
        #pragma unroll
        for (int i = 0; i < 6; ++i)
            __builtin_amdgcn_global_load_lds(
                (const __attribute__((address_space(1))) void*)(gsrc[i]),
                (__attribute__((address_space(3))) void*)(lb + loff[i]), 16, 0, 0);
    }

    const int fr = l & 15, kb = l >> 4;
    const int sw_rd = ((kb ^ (l & 3)) << 4);

    for (int kc = 0; kc < 16; ++kc) {
        __syncthreads();
        if (kc < 15) {
            char* lb = smem + ((kc + 1) & 1) * 24576;
            const int kbyt = (kc + 1) * 64;
            #pragma unroll
            for (int i = 0; i < 6; ++i)
                __builtin_amdgcn_global_load_lds(
                    (const __attribute__((address_space(1))) void*)(gsrc[i] + kbyt),
                    (__attribute__((address_space(3))) void*)(lb + loff[i]), 16, 0, 0);
        }
        const char* lb = smem + (kc & 1) * 24576;

        const int abyt = (w * 16 + fr) * 64 + sw_rd;
        half8v ahi  = *(const half8v*)(lb + abyt);
        half8v alo  = *(const half8v*)(lb + 4096 + abyt);
        half8v ahid = ahi * (_Float16)SPLIT_INV;
        #pragma unroll
        for (int nf = 0; nf < 8; ++nf) {
            const int bbyt = (nf * 16 + fr) * 64 + sw_rd;
            half8v bhi  = *(const half8v*)(lb + 8192 + bbyt);
            half8v blo  = *(const half8v*)(lb + 16384 + bbyt);
            half8v bhid = bhi * (_Float16)SPLIT_INV;
            acc[nf] = __builtin_amdgcn_mfma_f32_16x16x32_f16(ahi,  bhi,  acc[nf], 0, 0, 0);
            acc[nf] = __builtin_amdgcn_mfma_f32_16x16x32_f16(ahid, blo,  acc[nf], 0, 0, 0);
            acc[nf] = __builtin_amdgcn_mfma_f32_16x16x32_f16(alo,  bhid, acc[nf], 0, 0, 0);
        }
    }

    // ---- tanh + split-store epilogue ----
    float bo[8];
    #pragma unroll
    for (int nf = 0; nf < 8; ++nf) bo[nf] = bias[c0 + nf * 16 + fr];

    #pragma unroll
    for (int q = 0; q < 4; ++q) {
        const int r = r0 + w * 16 + kb * 4 + q;
        #pragma unroll
        for (int nf = 0; nf < 8; ++nf) {
            const float o = tanhf(acc[nf][q] + bo[nf]);
            const _Float16 oh = (_Float16)o;
            const size_t idx = (size_t)r * Hdim + c0 + nf * 16 + fr;
            hiP[idx] = oh;
            loP[idx] = (_Float16)((o - (float)oh) * SPLIT_SC);
        }
    }
}

// ---------------------------------------------------------------------------
// MFMA GRU step — WIDENED TILE (round 10): 128 rows x 64 cols x 3 gates,
// BK=32, 4 waves. Rationale: round-9 counters (MfmaUtil 29%, ~850 cyc
// stall/chunk at the vmcnt(0) barrier drain) -> double per-chunk compute
// (72 MFMA/wave vs 36) against the same one-phase load latency.
// LDS 40 KB/buffer double-buffered (80 KB): Ahi|Alo (16 KB) + Bhi|Blo (24 KB).
// Same 16B-slot XOR swizzle (pre-swizzled global src; read = same involution).
// Numerics identical to round-9 kernel (same per-output accumulation order).
// ---------------------------------------------------------------------------
__global__ __launch_bounds__(256, 2) void k_gru(
    const _Float16* __restrict__ hiIn, const _Float16* __restrict__ loIn,
    const _Float16* __restrict__ uthi, const _Float16* __restrict__ utlo,
    const float* __restrict__ gbias,   // [2][1536]
    const float* __restrict__ emb_k,   // [128][1536] (includes bias0)
    const int* __restrict__ sym,
    int step,
    _Float16* __restrict__ hiOut, _Float16* __restrict__ loOut,
    float* __restrict__ hF) {          // non-null on last step: f32 h_t out

    constexpr int BUFSZ = 40960;       // Ahi 0 | Alo 8192 | Bhi 16384 | Blo 28672
    __shared__ __align__(16) char smem[2 * BUFSZ];
    const int tid = threadIdx.x;
    const int l = tid & 63, w = tid >> 6;

    // XCD swizzle: 1024 blocks = 8 XCDs x 128 (bijective, 1024%8==0);
    // 8 consecutive swz share a 128-row A panel in the XCD's L2.
    const int bid = blockIdx.x;
    const int swz = (bid & 7) * 128 + (bid >> 3);
    const int rb = swz >> 3, cb = swz & 7;
    const int m0 = rb * 128, c0 = cb * 64;

    // ---- staging tables: 10 global_load_lds segments per wave ----
    // A: 16 segs (8 hi + 8 lo, 128 rows each plane); B: 24 segs (12+12, 192 rows).
    const char* gsrc[10];
    int loff[10];
    {
        int n = 0;
        #pragma unroll
        for (int s0 = 0; s0 < 4; ++s0) {        // A segs: s = w + s0*4 in [0,16)
            const int s = w + s0 * 4;
            const _Float16* pl = (s < 8) ? hiIn : loIn;
            const int seg = s & 7;
            const int grow = seg * 16 + (l >> 2);
            const int slot = (l & 3) ^ (grow & 3);
            gsrc[n] = (const char*)(pl + (size_t)(m0 + grow) * Hdim) + slot * 16;
            loff[n] = ((s < 8) ? 0 : 8192) + seg * 1024;
            ++n;
        }
        #pragma unroll
        for (int s0 = 0; s0 < 6; ++s0) {        // B segs: t = w + s0*4 in [0,24)
            const int t = w + s0 * 4;
            const _Float16* pl = (t < 12) ? uthi : utlo;
            const int seg = (t < 12) ? t : t - 12;
            const int jrow = seg * 16 + (l >> 2);   // [0,192): gate-major
            const int g = jrow >> 6, jl = jrow & 63;
            const int slot = (l & 3) ^ (jrow & 3);
            gsrc[n] = (const char*)(pl + (size_t)(g * Hdim + c0 + jl) * Hdim) + slot * 16;
            loff[n] = 16384 + ((t < 12) ? 0 : 12288) + seg * 1024;
            ++n;
        }
    }

    f32x4 acc[2][4][3] = {};   // [mf][nf][gate]

    // prologue: stage chunk 0 into buffer 0
    {
        char* lb = smem;
        #pragma unroll
        for (int i = 0; i < 10; ++i)
            __builtin_amdgcn_global_load_lds(
                (const __attribute__((address_space(1))) void*)(gsrc[i]),
                (__attribute__((address_space(3))) void*)(lb + loff[i]), 16, 0, 0);
    }

    const int fr = l & 15;                 // fragment row/col index
    const int kb_lane = l >> 4;            // k-block 0..3
    const int sw_rd = ((kb_lane ^ (l & 3)) << 4);

    for (int kc = 0; kc < 16; ++kc) {
        __syncthreads();                   // drains vm+lgkm: buf[kc&1] ready
        if (kc < 15) {
            char* lb = smem + ((kc + 1) & 1) * BUFSZ;
            const int kbyt = (kc + 1) * 64;
            #pragma unroll
            for (int i = 0; i < 10; ++i)
                __builtin_amdgcn_global_load_lds(
                    (const __attribute__((address_space(1))) void*)(gsrc[i] + kbyt),
                    (__attribute__((address_space(3))) void*)(lb + loff[i]), 16, 0, 0);
        }
        const char* lb = smem + (kc & 1) * BUFSZ;

        half8v ahi[2], alo[2], ahid[2];
        #pragma unroll
        for (int mf = 0; mf < 2; ++mf) {
            const int r = w * 32 + mf * 16 + fr;
            const int byt = r * 64 + sw_rd;
            ahi[mf]  = *(const half8v*)(lb + byt);
            alo[mf]  = *(const half8v*)(lb + 8192 + byt);
            ahid[mf] = ahi[mf] * (_Float16)SPLIT_INV;
        }
        #pragma unroll
        for (int g = 0; g < 3; ++g) {
            #pragma unroll
            for (int nf = 0; nf < 4; ++nf) {
                const int jrow = g * 64 + nf * 16 + fr;
                const int byt = jrow * 64 + sw_rd;
                half8v bhi  = *(const half8v*)(lb + 16384 + byt);
                half8v blo  = *(const half8v*)(lb + 28672 + byt);
                half8v bhid = bhi * (_Float16)SPLIT_INV;
                #pragma unroll
                for (int mf = 0; mf < 2; ++mf) {
                    acc[mf][nf][g] = __builtin_amdgcn_mfma_f32_16x16x32_f16(
                        ahi[mf], bhi, acc[mf][nf][g], 0, 0, 0);
                    acc[mf][nf][g] = __builtin_amdgcn_mfma_f32_16x16x32_f16(
                        ahid[mf], blo, acc[mf][nf][g], 0, 0, 0);
                    acc[mf][nf][g] = __builtin_amdgcn_mfma_f32_16x16x32_f16(
                        alo[mf], bhid, acc[mf][nf][g], 0, 0, 0);
                }
            }
        }
    }

    // ---- GRU cell epilogue ----
    const float* bias1 = gbias + H3;
    float b1z[4], b1r[4], b1h[4];
    #pragma unroll
    for (int nf = 0; nf < 4; ++nf) {
        const int jg = c0 + nf * 16 + fr;
        b1z[nf] = bias1[jg];
        b1r[nf] = bias1[Hdim + jg];
        b1h[nf] = bias1[2 * Hdim + jg];
    }
    #pragma unroll
    for (int mf = 0; mf < 2; ++mf) {
        #pragma unroll
        for (int q = 0; q < 4; ++q) {
            const int r = m0 + w * 32 + mf * 16 + kb_lane * 4 + q;
            const float* xrow = (step == 0) ? gbias : (emb_k + (size_t)sym[r] * H3);
            #pragma unroll
            for (int nf = 0; nf < 4; ++nf) {
                const int jg = c0 + nf * 16 + fr;
                const float xz = xrow[jg];
                const float xr_ = xrow[Hdim + jg];
                const float xh = xrow[2 * Hdim + jg];
                const float az = acc[mf][nf][0][q];
                const float ar = acc[mf][nf][1][q];
                const float ah = acc[mf][nf][2][q];
                const size_t idx = (size_t)r * Hdim + jg;
                const float hold = (float)hiIn[idx] + (float)loIn[idx] * SPLIT_INV;
                const float z  = sigm(xz + b1z[nf] + az);
                const float rr = sigm(xr_ + b1r[nf] + ar);
                const float hh = tanhf(xh + rr * (b1h[nf] + ah));
                const float o = z * hold + (1.0f - z) * hh;
                const _Float16 oh = (_Float16)o;
                hiOut[idx] = oh;
                loOut[idx] = (_Float16)((o - (float)oh) * SPLIT_SC);
                if (hF) hF[idx] = o;
            }
        }
    }
}

// ---------------------------------------------------------------------------
// MFMA output head: logits = h @ Wout^T-split + bout, fused log-softmax /
// entropy / argmax, all register/shuffle resident. (validated round 6)
// ---------------------------------------------------------------------------
__global__ __launch_bounds__(256, 2) void k_out(
    const _Float16* __restrict__ hiP, const _Float16* __restrict__ loP,
    const _Float16* __restrict__ wthi, const _Float16* __restrict__ wtlo, // [128][512]
    const float* __restrict__ bout, int step,
    float* __restrict__ seqO, float* __restrict__ logO,
    float* __restrict__ entO, float* __restrict__ lenO,
    int* __restrict__ symO) {

    __shared__ __align__(16) char smem[2 * 24576];
    const int tid = threadIdx.x;
    const int l = tid & 63, w = tid >> 6;
    const int r0 = blockIdx.x * 64;

    const char* gsrc[6];
    int loff[6];
    {
        #pragma unroll
        for (int i = 0; i < 6; ++i) {
            const int s = w + i * 4;
            if (s < 8) {                       // A: h rows r0..r0+63, hi|lo
                const _Float16* pl = (s < 4) ? hiP : loP;
                const int seg = (s < 4) ? s : s - 4;
                const int grow = seg * 16 + (l >> 2);
                const int slot = (l & 3) ^ (grow & 3);
                gsrc[i] = (const char*)(pl + (size_t)(r0 + grow) * Hdim) + slot * 16;
                loff[i] = ((s < 4) ? 0 : 4096) + seg * 1024;
            } else {                           // B: wt rows 0..127, hi|lo
                const int t = s - 8;
                const _Float16* pl = (t < 8) ? wthi : wtlo;
                const int seg = (t < 8) ? t : t - 8;
                const int grow = seg * 16 + (l >> 2);
                const int slot = (l & 3) ^ (grow & 3);
                gsrc[i] = (const char*)(pl + (size_t)grow * Hdim) + slot * 16;
                loff[i] = 8192 + ((t < 8) ? 0 : 8192) + seg * 1024;
            }
        }
    }

    f32x4 acc[8] = {};   // [nf] : cols nf*16 + (l&15)

    {   // prologue: stage chunk 0 into buffer 0
        char* lb = smem;
        #pragma unroll
        for (int i = 0; i < 6; ++i)
            __builtin_amdgcn_global_load_lds(
                (const __attribute__((address_space(1))) void*)(gsrc[i]),
                (__attribute__((address_space(3))) void*)(lb + loff[i]), 16, 0, 0);
    }

    const int fr = l & 15, kb = l >> 4;
    const int sw_rd = ((kb ^ (l & 3)) << 4);

    for (int kc = 0; kc < 16; ++kc) {
        __syncthreads();
        if (kc < 15) {
            char* lb = smem + ((kc + 1) & 1) * 24576;
            const int kbyt = (kc + 1) * 64;
            #pragma unroll
            for (int i = 0; i < 6; ++i)
                __builtin_amdgcn_global_load_lds(
                    (const __attribute__((address_space(1))) void*)(gsrc[i] + kbyt),
                    (__attribute__((address_space(3))) void*)(lb + loff[i]), 16, 0, 0);
        }
        const char* lb = smem + (kc & 1) * 24576;

        const int abyt = (w * 16 + fr) * 64 + sw_rd;
        half8v ahi  = *(const half8v*)(lb + abyt);
        half8v alo  = *(const half8v*)(lb + 4096 + abyt);
        half8v ahid = ahi * (_Float16)SPLIT_INV;
        #pragma unroll
        for (int nf = 0; nf < 8; ++nf) {
            const int bbyt = (nf * 16 + fr) * 64 + sw_rd;
            half8v bhi  = *(const half8v*)(lb + 8192 + bbyt);
            half8v blo  = *(const half8v*)(lb + 16384 + bbyt);
            half8v bhid = bhi * (_Float16)SPLIT_INV;
            acc[nf] = __builtin_amdgcn_mfma_f32_16x16x32_f16(ahi,  bhi,  acc[nf], 0, 0, 0);
            acc[nf] = __builtin_amdgcn_mfma_f32_16x16x32_f16(ahid, blo,  acc[nf], 0, 0, 0);
            acc[nf] = __builtin_amdgcn_mfma_f32_16x16x32_f16(alo,  bhid, acc[nf], 0, 0, 0);
        }
    }

    // ---- fused log-softmax / entropy / argmax epilogue ----
    float bo[8];
    #pragma unroll
    for (int nf = 0; nf < 8; ++nf) bo[nf] = bout[nf * 16 + fr];

    #pragma unroll
    for (int q = 0; q < 4; ++q) {
        float vals[8];
        #pragma unroll
        for (int nf = 0; nf < 8; ++nf) vals[nf] = acc[nf][q] + bo[nf];

        float vmax = vals[0]; int vidx = fr;
        #pragma unroll
        for (int nf = 1; nf < 8; ++nf)
            if (vals[nf] > vmax) { vmax = vals[nf]; vidx = nf * 16 + fr; }
        #pragma unroll
        for (int off = 1; off < 16; off <<= 1) {
            const float ov = __shfl_xor(vmax, off);
            const int   oi = __shfl_xor(vidx, off);
            if (ov > vmax || (ov == vmax && oi < vidx)) { vmax = ov; vidx = oi; }
        }

        float s = 0.0f, t2 = 0.0f;
        #pragma unroll
        for (int nf = 0; nf < 8; ++nf) {
            const float d = vals[nf] - vmax;
            const float e = __expf(d);
            s += e; t2 = fmaf(e, d, t2);
        }
        #pragma unroll
        for (int off = 1; off < 16; off <<= 1) {
            s  += __shfl_xor(s, off);
            t2 += __shfl_xor(t2, off);
        }

        if (fr == 0) {
            const int rg = r0 + w * 16 + kb * 4 + q;
            const float logS = logf(s);
            const float ent  = logS - t2 / s;
            seqO[rg * Lmsg + step] = (float)vidx;
            logO[rg * Lmsg + step] = -logS;
            symO[rg] = vidx;
            if (step == 0) { entO[rg] = ent * (1.0f / Lmsg); lenO[rg] = (float)Lmsg; }
            else           { entO[rg] += ent * (1.0f / Lmsg); }
        }
    }
}

} // namespace

extern "C" void kernel_launch(void* const* d_in, const int* in_sizes, int n_in,
                              void* d_out, int out_size, void* d_ws, size_t ws_size,
                              hipStream_t stream) {
    (void)in_sizes; (void)n_in; (void)out_size; (void)ws_size;

    const float* inputs = (const float*)d_in[0];
    const float* W_vh   = (const float*)d_in[1];
    const float* b_vh   = (const float*)d_in[2];
    const float* gk     = (const float*)d_in[3];
    const float* guk    = (const float*)d_in[4];
    const float* gbias  = (const float*)d_in[5];   // [2][3H]
    const float* Wout   = (const float*)d_in[6];
    const float* bout   = (const float*)d_in[7];
    const float* emb    = (const float*)d_in[8];

    float* out  = (float*)d_out;
    float* seqO = out;
    float* logO = out + (size_t)Bsz * Lmsg;
    float* entO = out + (size_t)2 * Bsz * Lmsg;
    float* lenO = entO + Bsz;
    float* hF   = lenO + Bsz;                       // [B,H] f32 final h_t

    char* wsb = (char*)d_ws;
    const size_t PLANE = (size_t)Bsz * Hdim * sizeof(_Float16);  // 16 MiB
    _Float16* pH[2] = { (_Float16*)(wsb),             (_Float16*)(wsb + 2 * PLANE) };
    _Float16* pL[2] = { (_Float16*)(wsb + PLANE),     (_Float16*)(wsb + 3 * PLANE) };
    // inputs hi/lo planes live in pH[1]/pL[1]'s space (dead until gru step 0)
    _Float16* aHi   = pH[1];
    _Float16* aLo   = pL[1];
    _Float16* uthi  = (_Float16*)(wsb + 4 * PLANE);
    _Float16* utlo  = uthi + (size_t)H3 * Hdim;
    _Float16* wthi  = utlo + (size_t)H3 * Hdim;
    _Float16* wtlo  = wthi + (size_t)Vdim * Hdim;
    _Float16* wvhi  = wtlo + (size_t)Vdim * Hdim;
    _Float16* wvlo  = wvhi + (size_t)Hdim * Hdim;
    float*    emb_k = (float*)(wvlo + (size_t)Hdim * Hdim);
    int*      sym   = (int*)(emb_k + (size_t)Vdim * H3);

    k_embk  <<<dim3(Vdim * H3 / 256), 256, 0, stream>>>(emb, gk, gbias, emb_k, sym);
    k_split <<<dim3(H3 * Hdim / 256), 256, 0, stream>>>(guk, uthi, utlo, H3);
    k_split <<<dim3(Vdim * Hdim / 256), 256, 0, stream>>>(Wout, wthi, wtlo, Vdim);
    k_split <<<dim3(Hdim * Hdim / 256), 256, 0, stream>>>(W_vh, wvhi, wvlo, Hdim);
    k_asplit<<<dim3(Bsz * Fdim / 1024), 256, 0, stream>>>(inputs, aHi, aLo);
    k_vision2<<<dim3((Bsz / 64) * 4), 256, 0, stream>>>(aHi, aLo, wvhi, wvlo, b_vh,
                                                        pH[0], pL[0]);

    for (int t = 0; t < Lmsg; ++t) {
        const int rd = t & 1, wr = (t + 1) & 1;
        k_gru<<<dim3((Bsz / 128) * (Hdim / 64)), 256, 0, stream>>>(
            pH[rd], pL[rd], uthi, utlo, gbias, emb_k, sym, t,
            pH[wr], pL[wr], (t == Lmsg - 1) ? hF : nullptr);
        k_out<<<dim3(Bsz / 64), 256, 0, stream>>>(
            pH[wr], pL[wr], wthi, wtlo, bout, t, seqO, logO, entO, lenO, sym);
    }
}